// Round 20
// baseline (420.663 us; speedup 1.0000x reference)
//
#include <hip/hip_runtime.h>

#define NB 16
#define NA 261888
#define PRE 6000
#define POST 1000
#define CAP 8192
#define SEG 256
#define NSEG ((PRE + SEG - 1) / SEG)   // 24
#define BOXSTRIDE 6144
#define MROWS2 6144                    // mask rows per chunk (covers seg 23 diag)
#define KPAD 1024
#define CCHUNK 2048                    // rank col-split width (4 chunks over CAP)
#define THRF 0.972f
// Exact NMS predicate: RN32(inter/denom) > 0.7f  <=>  inter >= M*denom with
// M = midpoint(0.7f, nextafterf) = 0x1.666667p-1 (25-bit mantissa).
// f32-only form: fmaf(0.7f, denom, -inter) <= -2^-25*denom. Exact because
// M*denom - inter lies on a lattice of spacing 2^(ed-48) while the RN hazard
// band around -T is 2^(ed-49); equality (e==-T) included on both sides.

typedef unsigned int u32;
typedef unsigned long long u64;

__device__ __constant__ int NE_UNITS[10] = {0, 1, 2, 3, 5, 6, 7, 10, 11, 15};
__device__ __constant__ int TILE_N[3] = {4, 3, 3};
__device__ __constant__ int TILE_U[3][4] = {{0, 5, 10, 15}, {1, 2, 6, 0}, {3, 7, 11, 0}};

__device__ inline float box_area(float4 v) {
    return __fmul_rn(__fadd_rn(__fsub_rn(v.z, v.x), 1.0f),
                     __fadd_rn(__fsub_rn(v.w, v.y), 1.0f));
}

__device__ inline bool iou_supp(float4 a, float aa, float4 c, float ca) {
    float xx1 = fmaxf(c.x, a.x);
    float yy1 = fmaxf(c.y, a.y);
    float xx2 = fminf(c.z, a.z);
    float yy2 = fminf(c.w, a.w);
    float iw = fmaxf(__fadd_rn(__fsub_rn(xx2, xx1), 1.0f), 0.f);
    float ih = fmaxf(__fadd_rn(__fsub_rn(yy2, yy1), 1.0f), 0.f);
    float inter = __fmul_rn(iw, ih);
    float denom = __fsub_rn(__fadd_rn(ca, aa), inter);
    return __fmaf_rn(0.7f, denom, -inter) <= __fmul_rn(denom, -0x1p-25f);
}

// ---------------- anchors (match numpy float64 -> float32 exactly) -------------
__device__ inline void anchor_at(int idx, float& a0, float& a1, float& a2, float& a3) {
    int base, fw, stride, scale;
    if (idx < 196608)      { base = 0;      fw = 256; stride = 4;  scale = 4; }
    else if (idx < 245760) { base = 196608; fw = 128; stride = 8;  scale = 8; }
    else if (idx < 258048) { base = 245760; fw = 64;  stride = 16; scale = 16; }
    else if (idx < 261120) { base = 258048; fw = 32;  stride = 32; scale = 32; }
    else                   { base = 261120; fw = 16;  stride = 64; scale = 64; }
    int rel  = idx - base;
    int ri   = rel % 3;
    int cell = rel / 3;
    int col  = cell & (fw - 1);
    int row  = cell / fw;
    double cx = (col + 0.5) * (double)stride;
    double cy = (row + 0.5) * (double)stride;
    double sz = (double)scale * 8.0;
    double sq = (ri == 0) ? 0.7071067811865476 : ((ri == 1) ? 1.0 : 1.4142135623730951);
    double wsd = sz * sq;
    double hsd = sz / sq;
    a0 = (float)(cx - 0.5 * wsd);
    a1 = (float)(cy - 0.5 * hsd);
    a2 = (float)(cx + 0.5 * wsd);
    a3 = (float)(cy + 0.5 * hsd);
}

__device__ inline float4 decode_box(u64 key, int b, const float* __restrict__ deltas,
                                    float hmax, float wmax) {
    int a = (int)(~(u32)key);
    float a0, a1, a2, a3;
    anchor_at(a, a0, a1, a2, a3);
    const float4 d4 = *(const float4*)(deltas + ((size_t)b * NA + a) * 4);
    float w  = __fadd_rn(__fsub_rn(a2, a0), 1.0f);
    float h  = __fadd_rn(__fsub_rn(a3, a1), 1.0f);
    float cx = __fadd_rn(a0, __fmul_rn(0.5f, w));
    float cy = __fadd_rn(a1, __fmul_rn(0.5f, h));
    float pcx = __fadd_rn(__fmul_rn(d4.x, w), cx);
    float pcy = __fadd_rn(__fmul_rn(d4.y, h), cy);
    float pw  = __fmul_rn((float)exp((double)d4.z), w);
    float ph  = __fmul_rn((float)exp((double)d4.w), h);
    float x1 = __fsub_rn(pcx, __fmul_rn(0.5f, pw));
    float y1 = __fsub_rn(pcy, __fmul_rn(0.5f, ph));
    float x2 = __fadd_rn(pcx, __fmul_rn(0.5f, pw));
    float y2 = __fadd_rn(pcy, __fmul_rn(0.5f, ph));
    x1 = fminf(fmaxf(x1, 0.f), wmax);
    x2 = fminf(fmaxf(x2, 0.f), wmax);
    y1 = fminf(fmaxf(y1, 0.f), hmax);
    y2 = fminf(fmaxf(y2, 0.f), hmax);
    return make_float4(x1, y1, x2, y2);
}

// ---------------- fast path: fixed-threshold compact, block-aggregated ---------
__global__ void compact_fixed(const float* __restrict__ probs, u32* __restrict__ cntp,
                              u64* __restrict__ cand) {
    __shared__ u32 lcnt;
    __shared__ u32 lbase;
    int tid = threadIdx.x;
    int a = blockIdx.x * 256 + tid;
    int b = blockIdx.y;
    if (tid == 0) lcnt = 0;
    __syncthreads();
    float2 pv = *(const float2*)(probs + ((size_t)b * NA + a) * 2);
    float s = pv.y;
    u32 bits = __float_as_uint(s);
    int lpos = -1;
    if (s >= THRF) lpos = (int)atomicAdd(&lcnt, 1u);
    __syncthreads();
    if (tid == 0) lbase = lcnt ? atomicAdd(&cntp[b * 64], lcnt) : 0u;
    __syncthreads();
    if (lpos >= 0) {
        u32 pos = lbase + (u32)lpos;
        if (pos < CAP)
            cand[(size_t)b * CAP + pos] = ((u64)bits << 32) | (u32)(~(u32)a);
    }
}

// ---------------- validate fast path; set per-batch fallback flags -------------
__global__ void check_kernel(u32* __restrict__ cntp, u32* __restrict__ flag) {
    int t = threadIdx.x;
    if (t < NB) {
        u32 c = cntp[t * 64];
        u32 bad = (c < (u32)PRE || c > (u32)CAP) ? 1u : 0u;
        flag[t * 64] = bad;
        if (bad) cntp[t * 64] = 0;
    }
}

// ---------------- gated fallback: zero hist ------------------------------------
__global__ void zero_hist(const u32* __restrict__ flag, u32* __restrict__ hist) {
    int b = blockIdx.y;
    if (flag[b * 64] == 0) return;
    int i = blockIdx.x * 256 + threadIdx.x;
    hist[(size_t)b * 65536 + i] = 0;
}

// ---------------- gated fallback: histogram ------------------------------------
__global__ void hist_kernel(const u32* __restrict__ flag, const float* __restrict__ probs,
                            u32* __restrict__ hist) {
    int b = blockIdx.y;
    if (flag[b * 64] == 0) return;
    int a = blockIdx.x * 256 + threadIdx.x;
    float2 pv = *(const float2*)(probs + ((size_t)b * NA + a) * 2);
    u32 bits = __float_as_uint(pv.y);
    atomicAdd(&hist[(size_t)b * 65536 + (bits >> 16)], 1u);
}

// ---------------- gated fallback: per-batch threshold --------------------------
__global__ __launch_bounds__(1024) void thresh_kernel(const u32* __restrict__ flag,
                                                      const u32* __restrict__ hist,
                                                      u32* __restrict__ thr) {
    int b = blockIdx.x;
    if (flag[b * 64] == 0) return;
    __shared__ u32 csum[1024];
    int t = threadIdx.x;
    const u32* h = hist + (size_t)b * 65536;
    u32 s = 0;
    for (int k = 0; k < 64; k++) s += h[t * 64 + k];
    csum[t] = s;
    __syncthreads();
    if (t == 0) {
        u32 cum = 0;
        int bucket = 0;
        for (int c = 1023; c >= 0; c--) {
            if (cum + csum[c] >= (u32)PRE) {
                u32 cum2 = cum;
                for (int k = 63; k >= 0; k--) {
                    cum2 += h[c * 64 + k];
                    if (cum2 >= (u32)PRE) { bucket = c * 64 + k; break; }
                }
                break;
            }
            cum += csum[c];
        }
        thr[b] = (u32)bucket << 16;
    }
}

// ---------------- gated fallback: compact with exact threshold -----------------
__global__ void compact2_kernel(const u32* __restrict__ flag, const float* __restrict__ probs,
                                const u32* __restrict__ thr, u32* __restrict__ cntp,
                                u64* __restrict__ cand) {
    int b = blockIdx.y;
    if (flag[b * 64] == 0) return;
    __shared__ u32 lcnt;
    __shared__ u32 lbase;
    int tid = threadIdx.x;
    int a = blockIdx.x * 256 + tid;
    if (tid == 0) lcnt = 0;
    __syncthreads();
    float2 pv = *(const float2*)(probs + ((size_t)b * NA + a) * 2);
    u32 bits = __float_as_uint(pv.y);
    int lpos = -1;
    if (bits >= thr[b]) lpos = (int)atomicAdd(&lcnt, 1u);
    __syncthreads();
    if (tid == 0) lbase = lcnt ? atomicAdd(&cntp[b * 64], lcnt) : 0u;
    __syncthreads();
    if (lpos >= 0) {
        u32 pos = lbase + (u32)lpos;
        if (pos < CAP)
            cand[(size_t)b * CAP + pos] = ((u64)bits << 32) | (u32)(~(u32)a);
    }
}

// ---------------- all-pairs rank, 4-way column-split (full occupancy) ----------
__global__ __launch_bounds__(256) void rank_kernel(const u64* __restrict__ cand,
                                                   const u32* __restrict__ cntp,
                                                   u32* __restrict__ rank4) {
    __shared__ u64 ckey[256];
    int rt = blockIdx.x;
    int cchunk = blockIdx.y;
    int b = blockIdx.z;
    int cnt = (int)min(cntp[b * 64], (u32)CAP);
    int t = threadIdx.x;
    const u64* cb = cand + (size_t)b * CAP;
    int row = rt * 256 + t;
    u64 rkey = (row < cnt) ? cb[row] : ~0ULL;
    u32 acc = 0;
    int c0 = cchunk * CCHUNK;
    int c1 = c0 + CCHUNK; if (c1 > cnt) c1 = cnt;
    for (int cc0 = c0; cc0 < c1; cc0 += 256) {
        __syncthreads();
        int ci = cc0 + t;
        ckey[t] = (ci < c1) ? cb[ci] : 0ULL;   // key 0 < any valid key -> contributes 0
        __syncthreads();
        int lim = c1 - cc0; if (lim > 256) lim = 256;
        int c = 0;
        for (; c + 4 <= lim; c += 4) {
            u64 k0 = ckey[c], k1 = ckey[c + 1], k2 = ckey[c + 2], k3 = ckey[c + 3];
            acc += (k0 > rkey) ? 1u : 0u;
            acc += (k1 > rkey) ? 1u : 0u;
            acc += (k2 > rkey) ? 1u : 0u;
            acc += (k3 > rkey) ? 1u : 0u;
        }
        for (; c < lim; ++c) acc += (ckey[c] > rkey) ? 1u : 0u;
    }
    rank4[(((size_t)b * 4 + cchunk) * CAP) + row] = acc;
}

// ---------------- scatter decode: gBoxes[rank[i]] = decode(cand[i]) ------------
__global__ void scatter_decode(const u64* __restrict__ cand, const u32* __restrict__ cntp,
                               const u32* __restrict__ rank4, const float* __restrict__ deltas,
                               const float* __restrict__ img_info, float4* __restrict__ gBoxes,
                               float* __restrict__ gAreas, float* __restrict__ out) {
    int i = blockIdx.x * 256 + threadIdx.x;     // 0..8191
    int b = blockIdx.y;
    if (i < POST) {
        float* o = out + ((size_t)b * POST + i) * 5;
        o[0] = (float)b; o[1] = 0.f; o[2] = 0.f; o[3] = 0.f; o[4] = 0.f;
    }
    int cnt = (int)min(cntp[b * 64], (u32)CAP);
    if (i >= cnt) return;
    u32 r = rank4[(((size_t)b * 4 + 0) * CAP) + i]
          + rank4[(((size_t)b * 4 + 1) * CAP) + i]
          + rank4[(((size_t)b * 4 + 2) * CAP) + i]
          + rank4[(((size_t)b * 4 + 3) * CAP) + i];
    if (r >= (u32)BOXSTRIDE) return;
    float hmax = __fsub_rn(img_info[b * 3 + 0], 1.0f);
    float wmax = __fsub_rn(img_info[b * 3 + 1], 1.0f);
    float4 bx = decode_box(cand[(size_t)b * CAP + i], b, deltas, hmax, wmax);
    gBoxes[(size_t)b * BOXSTRIDE + r] = bx;
    gAreas[(size_t)b * BOXSTRIDE + r] = box_area(bx);
}

// ---------------- full suppression bitmask (pad LDS, col-batch 4) --------------
__global__ __launch_bounds__(256) void mask_kernel(const float4* __restrict__ gBoxes,
                                                   const float* __restrict__ gAreas,
                                                   u32* __restrict__ maskC) {
    __shared__ float4 cbox[256];
    __shared__ float  carea[256];
    __shared__ u32    tileOut[256][9];          // pad 8->9: conflict-free stores
    int lin = blockIdx.x;          // 0..299 over (rt, cc), cc >= rt
    int b = blockIdx.y;
    int rt = 0, rem = lin;
    while (rem >= NSEG - rt) { rem -= NSEG - rt; ++rt; }
    int cc = rt + rem;
    int t = threadIdx.x;
    int l = t & 63, q = t >> 6;
    const float4* gb = gBoxes + (size_t)b * BOXSTRIDE;
    const float*  ga = gAreas + (size_t)b * BOXSTRIDE;
    cbox[t] = gb[cc * 256 + t];
    carea[t] = ga[cc * 256 + t];
    float4 rb[4]; float ra[4]; int gr[4];
    #pragma unroll
    for (int j = 0; j < 4; ++j) {
        gr[j] = rt * 256 + l + 64 * j;
        rb[j] = gb[gr[j]];
        ra[j] = ga[gr[j]];
    }
    __syncthreads();
    int colbase = cc * 256 + q * 64;
    u32 accw[8] = {0u, 0u, 0u, 0u, 0u, 0u, 0u, 0u};
    #pragma unroll 2
    for (int cb4 = 0; cb4 < 64; cb4 += 4) {
        // batch-read 4 cols into registers (independent loads, one lgkm wait)
        float4 cx0 = cbox[q * 64 + cb4 + 0];
        float4 cx1 = cbox[q * 64 + cb4 + 1];
        float4 cx2 = cbox[q * 64 + cb4 + 2];
        float4 cx3 = cbox[q * 64 + cb4 + 3];
        float  cv0 = carea[q * 64 + cb4 + 0];
        float  cv1 = carea[q * 64 + cb4 + 1];
        float  cv2 = carea[q * 64 + cb4 + 2];
        float  cv3 = carea[q * 64 + cb4 + 3];
        int word = cb4 >> 5;               // 0 or 1 within this wave's 2 words
        int sh = cb4 & 31;
        u32 bits0 = 0, bits1 = 0, bits2 = 0, bits3 = 0;
        #pragma unroll
        for (int j = 0; j < 4; ++j) {
            int g0 = colbase + cb4;
            bits0 |= ((g0     > gr[j]) && iou_supp(rb[j], ra[j], cx0, cv0)) ? (1u << j) : 0u;
            bits1 |= ((g0 + 1 > gr[j]) && iou_supp(rb[j], ra[j], cx1, cv1)) ? (1u << j) : 0u;
            bits2 |= ((g0 + 2 > gr[j]) && iou_supp(rb[j], ra[j], cx2, cv2)) ? (1u << j) : 0u;
            bits3 |= ((g0 + 3 > gr[j]) && iou_supp(rb[j], ra[j], cx3, cv3)) ? (1u << j) : 0u;
        }
        #pragma unroll
        for (int j = 0; j < 4; ++j) {
            u32 m = (((bits0 >> j) & 1u))
                  | (((bits1 >> j) & 1u) << 1)
                  | (((bits2 >> j) & 1u) << 2)
                  | (((bits3 >> j) & 1u) << 3);
            accw[j * 2 + word] |= m << sh;
        }
    }
    #pragma unroll
    for (int j = 0; j < 4; ++j) {
        tileOut[l + 64 * j][2 * q]     = accw[j * 2 + 0];
        tileOut[l + 64 * j][2 * q + 1] = accw[j * 2 + 1];
    }
    __syncthreads();
    uint4* rec = (uint4*)(maskC + (((size_t)b * NSEG + cc) * MROWS2 + rt * 256 + t) * 8);
    rec[0] = make_uint4(tileOut[t][0], tileOut[t][1], tileOut[t][2], tileOut[t][3]);
    rec[1] = make_uint4(tileOut[t][4], tileOut[t][5], tileOut[t][6], tileOut[t][7]);
}

// ---------------- pipelined mask-driven greedy NMS scan ------------------------
__global__ __launch_bounds__(1024) void nms_scan(const u32* __restrict__ maskC,
                                                 const float4* __restrict__ gBoxes,
                                                 float* __restrict__ out) {
    __shared__ u32 tile[2][SEG][8];
    __shared__ u32 aliveC[2][8];
    __shared__ u32 accW[2][8];
    __shared__ int keptList[POST];
    __shared__ int Kvar;

    int b = blockIdx.x;
    int t = threadIdx.x;
    int lane = t & 63;
    int w = t >> 6;
    const u32* mb = maskC + (size_t)b * NSEG * MROWS2 * 8;

    if (t < 8) {
        aliveC[0][t] = 0xFFFFFFFFu;
        accW[0][t] = 0u;
    } else if (t < 16) {
        accW[1][t - 8] = 0u;
    }
    if (t == 0) Kvar = 0;
    {   // prefetch tile 0
        const uint4* src = (const uint4*)mb;
        uint4* dst = (uint4*)&tile[0][0][0];
        for (int i = t; i < SEG * 2; i += 1024) dst[i] = src[i];
    }

    for (int s = 0; s < NSEG; ++s) {
        int bufc = s & 1, bufn = bufc ^ 1;
        __syncthreads();                    // barrier A
        int Kpre = Kvar;
        if (Kpre >= POST) break;            // uniform

        if (w == 0) {
            // ---- serial greedy scan of segment s (wave 0)
            u32 va = (lane < 8) ? aliveC[bufc][lane] : 0u;
            int KK = Kpre;
            while (true) {
                u64 balv = __ballot(va != 0u);
                if (balv == 0ULL) break;
                int wsel = __ffsll(balv) - 1;
                u32 word = __builtin_amdgcn_readlane(va, wsel);
                int r = (wsel << 5) + (__ffs(word) - 1);
                u32 trow = tile[bufc][r][lane & 7];
                if (lane == 8) keptList[KK] = s * SEG + r;
                u32 self = (lane == (r >> 5)) ? (1u << (r & 31)) : 0u;
                if (lane < 8) va &= ~(trow | self);
                ++KK;
                if (KK == POST) break;
            }
            if (lane == 0) Kvar = KK;
        } else if (s + 1 < NSEG) {
            // ---- bulk apply for chunk s+1: kepts [0, Kpre), 120 threads/word
            const u32* mbC = mb + (size_t)(s + 1) * (MROWS2 * 8);
            int wi = t & 7;
            int sub = (t - 64) >> 3;        // 0..119
            u32 part = 0;
            int j = sub;
            for (; j + 480 < Kpre; j += 480) {
                u32 x0 = mbC[(size_t)keptList[j] * 8 + wi];
                u32 x1 = mbC[(size_t)keptList[j + 120] * 8 + wi];
                u32 x2 = mbC[(size_t)keptList[j + 240] * 8 + wi];
                u32 x3 = mbC[(size_t)keptList[j + 360] * 8 + wi];
                part |= x0 | x1 | x2 | x3;
            }
            for (; j < Kpre; j += 120)
                part |= mbC[(size_t)keptList[j] * 8 + wi];
            if (part) atomicOr(&accW[bufn][wi], part);
            // ---- tile prefetch s+1 (8KB)
            const uint4* src = (const uint4*)(mbC + (size_t)(s + 1) * SEG * 8);
            uint4* dst = (uint4*)&tile[bufn][0][0];
            for (int i = t - 64; i < SEG * 2; i += 960) dst[i] = src[i];
        }
        __syncthreads();                    // barrier B

        int Kcur = Kvar;
        if (s + 1 < NSEG) {
            // ---- residual apply: delta kepts from scan(s)
            const u32* mbC = mb + (size_t)(s + 1) * (MROWS2 * 8);
            int delta8 = (Kcur - Kpre) * 8;
            for (int idx = t; idx < delta8; idx += 1024) {
                int j = Kpre + (idx >> 3);
                int wi = idx & 7;
                u32 x = mbC[(size_t)keptList[j] * 8 + wi];
                if (x) atomicOr(&accW[bufn][wi], x);
            }
        }
        __syncthreads();                    // barrier C

        if (s + 1 < NSEG) {
            if (t < 8) {
                int W = (s + 1) * 8 + t;
                u32 init = (W < 187) ? 0xFFFFFFFFu : ((W == 187) ? 0xFFFFu : 0u);
                aliveC[bufn][t] = init & ~accW[bufn][t];
            } else if (t < 16) {
                accW[bufc][t - 8] = 0u;     // recycle for chunk s+2
            }
        }
    }
    __syncthreads();

    int K = Kvar;
    const float4* gb = gBoxes + (size_t)b * BOXSTRIDE;
    for (int i = t; i < K; i += 1024) {
        int j = keptList[i];
        float4 bx = gb[j];
        float* o = out + ((size_t)b * POST + i) * 5;
        o[0] = (float)b; o[1] = bx.x; o[2] = bx.y; o[3] = bx.z; o[4] = bx.w;
    }
}

// ---------------- mid-ws tier: R14 pipelined fused lazy NMS --------------------
__global__ __launch_bounds__(1024) void nms_fused(const float4* __restrict__ gBoxes,
                                                  const float* __restrict__ gAreas,
                                                  float* __restrict__ out) {
    __shared__ float4 segBox[2][SEG];
    __shared__ float  segArea[2][SEG];
    __shared__ u32    tile[2][SEG][8];
    __shared__ u32    aliveW[2][8];
    __shared__ unsigned char aliveB[3][SEG];
    __shared__ float4 keptBox[KPAD];
    __shared__ float  keptArea[KPAD];
    __shared__ int    Kvar;

    int b = blockIdx.x;
    int t = threadIdx.x;
    int lane = t & 63;
    int w = t >> 6;
    if (t == 0) Kvar = 0;
    const float4* gb = gBoxes + (size_t)b * BOXSTRIDE;
    const float*  ga = gAreas + (size_t)b * BOXSTRIDE;

    if (t < SEG) {
        segBox[0][t] = gb[t];
        segArea[0][t] = ga[t];
    }
    __syncthreads();
    if (w < 10) {
        int u = NE_UNITS[w];
        int wc = u & 3, h = u >> 2;
        int c = wc * 64 + lane;
        float4 cb = segBox[0][c];
        float  ca = segArea[0][c];
        for (int r = h * 64; r < h * 64 + 64; ++r) {
            float4 rb = segBox[0][r];
            float  ra = segArea[0][r];
            bool bit = (r < c) && iou_supp(rb, ra, cb, ca);
            u64 bal = __ballot(bit);
            if (lane == 0) tile[0][r][2 * wc]     = (u32)bal;
            if (lane == 1) tile[0][r][2 * wc + 1] = (u32)(bal >> 32);
        }
    }
    if (t < SEG) {
        u64 bal = __ballot(true);
        if (lane == 0) aliveW[0][2 * w]     = (u32)bal;
        if (lane == 1) aliveW[0][2 * w + 1] = (u32)(bal >> 32);
    }

    int Kprev = 0;
    for (int s = 0; s < NSEG; ++s) {
        int bufc = s & 1, bufn = bufc ^ 1;
        __syncthreads();
        int Kcur = Kvar;
        if (Kcur >= POST) break;

        if (t < SEG) {
            if (s > 0) {
                bool al = aliveB[0][t] && aliveB[1][t] && aliveB[2][t];
                if (al && Kcur > Kprev) {
                    float4 rb = segBox[bufc][t];
                    float  ra = segArea[bufc][t];
                    int k = Kprev;
                    while (k < Kcur) {
                        bool d0 = iou_supp(keptBox[k], keptArea[k], rb, ra);
                        bool d1 = ((k + 1) < Kcur) & iou_supp(keptBox[k + 1], keptArea[k + 1], rb, ra);
                        bool d2 = ((k + 2) < Kcur) & iou_supp(keptBox[k + 2], keptArea[k + 2], rb, ra);
                        bool d3 = ((k + 3) < Kcur) & iou_supp(keptBox[k + 3], keptArea[k + 3], rb, ra);
                        if (d0 | d1 | d2 | d3) { al = false; break; }
                        k += 4;
                    }
                }
                u64 bal = __ballot(al);
                if (lane == 0) aliveW[bufc][2 * w]     = (u32)bal;
                if (lane == 1) aliveW[bufc][2 * w + 1] = (u32)(bal >> 32);
            }
            if (s + 1 < NSEG) {
                int g = (s + 1) * SEG + t;
                segBox[bufn][t] = gb[g];
                segArea[bufn][t] = ga[g];
                unsigned char v8 = (g < PRE) ? 1 : 0;
                aliveB[0][t] = v8; aliveB[1][t] = v8; aliveB[2][t] = v8;
            }
        }
        __syncthreads();

        if (w == 0) {
            int l = lane;
            u32 va = (l < 8) ? aliveW[bufc][l] : 0u;
            int KK = Kcur;
            while (true) {
                u64 balv = __ballot(va != 0u);
                if (balv == 0ULL) break;
                int wsel = __ffsll(balv) - 1;
                u32 word = __builtin_amdgcn_readlane(va, wsel);
                int r = (wsel << 5) + (__ffs(word) - 1);
                u32 trow = tile[bufc][r][l & 7];
                if (l >= 8 && l < 12)
                    ((float*)keptBox)[KK * 4 + (l - 8)] = ((const float*)segBox[bufc])[r * 4 + (l - 8)];
                if (l == 12) keptArea[KK] = segArea[bufc][r];
                u32 self = (l == (r >> 5)) ? (1u << (r & 31)) : 0u;
                if (l < 8) va &= ~(trow | self);
                ++KK;
                if (KK == POST) break;
            }
            if (l == 0) Kvar = KK;
        } else if (w <= 12) {
            if (s + 1 < NSEG && Kcur > 0) {
                int ww = w - 1;
                int rg = ww & 3;
                int kc = ww >> 2;
                int row = rg * 64 + lane;
                float4 rb = segBox[bufn][row];
                float  ra = segArea[bufn][row];
                bool dead = false, written = false;
                int q = 0;
                int k = kc;
                while (k < Kcur) {
                    int k1 = k + 3, k2 = k + 6, k3 = k + 9;
                    bool d0 = iou_supp(keptBox[k], keptArea[k], rb, ra);
                    bool d1 = (k1 < Kcur) & iou_supp(keptBox[k1], keptArea[k1], rb, ra);
                    bool d2 = (k2 < Kcur) & iou_supp(keptBox[k2], keptArea[k2], rb, ra);
                    bool d3 = (k3 < Kcur) & iou_supp(keptBox[k3], keptArea[k3], rb, ra);
                    dead |= (d0 | d1 | d2 | d3);
                    k += 12;
                    if (((++q) & 7) == 0) {
                        if (dead && !written) { aliveB[kc][row] = 0; written = true; }
                        u32 comb = (u32)aliveB[0][row] & (u32)aliveB[1][row] & (u32)aliveB[2][row];
                        if (__ballot(comb != 0u) == 0ULL) break;
                    }
                }
                if (dead && !written) aliveB[kc][row] = 0;
            }
        } else {
            if (s + 1 < NSEG) {
                int g3 = w - 13;
                int nu = TILE_N[g3];
                for (int ui = 0; ui < nu; ++ui) {
                    int u = TILE_U[g3][ui];
                    int wc = u & 3, h = u >> 2;
                    int c = wc * 64 + lane;
                    float4 cb = segBox[bufn][c];
                    float  ca = segArea[bufn][c];
                    for (int r = h * 64; r < h * 64 + 64; ++r) {
                        float4 rb = segBox[bufn][r];
                        float  ra = segArea[bufn][r];
                        bool bit = (r < c) && iou_supp(rb, ra, cb, ca);
                        u64 bal = __ballot(bit);
                        if (lane == 0) tile[bufn][r][2 * wc]     = (u32)bal;
                        if (lane == 1) tile[bufn][r][2 * wc + 1] = (u32)(bal >> 32);
                    }
                }
            }
        }
        Kprev = Kcur;
    }
    __syncthreads();

    int K = Kvar;
    for (int s2 = t; s2 < POST; s2 += 1024) {
        float* o = out + ((size_t)b * POST + s2) * 5;
        if (s2 < K) {
            float4 bx = keptBox[s2];
            o[0] = (float)b; o[1] = bx.x; o[2] = bx.y; o[3] = bx.z; o[4] = bx.w;
        } else {
            o[0] = (float)b; o[1] = 0.f; o[2] = 0.f; o[3] = 0.f; o[4] = 0.f;
        }
    }
}

// ---------------- fallback: monolithic sort+decode+NMS (small ws) --------------
__global__ __launch_bounds__(1024) void final_kernel(const u64* __restrict__ cand, const u32* __restrict__ cntp,
                             const float* __restrict__ deltas, const float* __restrict__ img_info,
                             float* __restrict__ out) {
    __shared__ union {
        u64 keys[CAP];
        struct {
            float boxes[PRE][4];
            float areas[PRE];
            u32   alive[192];
        } n;
    } sh;
    __shared__ int s_next;

    int b = blockIdx.x;
    int tid = threadIdx.x;

    for (int s = tid; s < POST; s += 1024) {
        float* o = out + ((size_t)b * POST + s) * 5;
        o[0] = (float)b; o[1] = 0.f; o[2] = 0.f; o[3] = 0.f; o[4] = 0.f;
    }

    int n = (int)min(cntp[b * 64], (u32)CAP);
    for (int i = tid; i < CAP; i += 1024)
        sh.keys[i] = (i < n) ? cand[(size_t)b * CAP + i] : 0ULL;
    __syncthreads();

    for (int k = 2; k <= CAP; k <<= 1) {
        for (int j = k >> 1; j > 0; j >>= 1) {
            for (int i = tid; i < CAP; i += 1024) {
                int ixj = i ^ j;
                if (ixj > i) {
                    u64 x = sh.keys[i], y = sh.keys[ixj];
                    bool desc = ((i & k) == 0);
                    if (desc ? (x < y) : (x > y)) { sh.keys[i] = y; sh.keys[ixj] = x; }
                }
            }
            __syncthreads();
        }
    }

    u32 myIdx[6];
    #pragma unroll
    for (int r = 0; r < 6; r++) {
        int i = tid + r * 1024;
        if (i < PRE) myIdx[r] = ~(u32)(sh.keys[i]);
    }
    __syncthreads();

    float hmax = __fsub_rn(img_info[b * 3 + 0], 1.0f);
    float wmax = __fsub_rn(img_info[b * 3 + 1], 1.0f);

    #pragma unroll
    for (int r = 0; r < 6; r++) {
        int i = tid + r * 1024;
        if (i < PRE) {
            int a = (int)myIdx[r];
            float a0, a1, a2, a3;
            anchor_at(a, a0, a1, a2, a3);
            const float4 d4 = *(const float4*)(deltas + ((size_t)b * NA + a) * 4);
            float w  = __fadd_rn(__fsub_rn(a2, a0), 1.0f);
            float h  = __fadd_rn(__fsub_rn(a3, a1), 1.0f);
            float cx = __fadd_rn(a0, __fmul_rn(0.5f, w));
            float cy = __fadd_rn(a1, __fmul_rn(0.5f, h));
            float pcx = __fadd_rn(__fmul_rn(d4.x, w), cx);
            float pcy = __fadd_rn(__fmul_rn(d4.y, h), cy);
            float pw  = __fmul_rn((float)exp((double)d4.z), w);
            float ph  = __fmul_rn((float)exp((double)d4.w), h);
            float x1 = __fsub_rn(pcx, __fmul_rn(0.5f, pw));
            float y1 = __fsub_rn(pcy, __fmul_rn(0.5f, ph));
            float x2 = __fadd_rn(pcx, __fmul_rn(0.5f, pw));
            float y2 = __fadd_rn(pcy, __fmul_rn(0.5f, ph));
            x1 = fminf(fmaxf(x1, 0.f), wmax);
            x2 = fminf(fmaxf(x2, 0.f), wmax);
            y1 = fminf(fmaxf(y1, 0.f), hmax);
            y2 = fminf(fmaxf(y2, 0.f), hmax);
            sh.n.boxes[i][0] = x1; sh.n.boxes[i][1] = y1;
            sh.n.boxes[i][2] = x2; sh.n.boxes[i][3] = y2;
            sh.n.areas[i] = __fmul_rn(__fadd_rn(__fsub_rn(x2, x1), 1.0f),
                                      __fadd_rn(__fsub_rn(y2, y1), 1.0f));
        }
    }

    for (int wdi = tid; wdi < 192; wdi += 1024) {
        u32 v = 0xFFFFFFFFu;
        if (wdi == 187) v = 0x0000FFFFu;
        if (wdi > 187)  v = 0u;
        sh.n.alive[wdi] = v;
    }
    __syncthreads();

    int kept = 0;
    int scanWord = 0;
    while (kept < POST) {
        if (tid == 0) {
            int found = -1;
            while (scanWord < 188) {
                u32 wv = sh.n.alive[scanWord];
                if (wv) { found = scanWord * 32 + (__ffs(wv) - 1); break; }
                scanWord++;
            }
            s_next = found;
        }
        __syncthreads();
        int i = s_next;
        if (i < 0) break;
        float bx1 = sh.n.boxes[i][0], by1 = sh.n.boxes[i][1];
        float bx2 = sh.n.boxes[i][2], by2 = sh.n.boxes[i][3];
        float bar = sh.n.areas[i];
        if (tid == 0) {
            float* o = out + ((size_t)b * POST + kept) * 5;
            o[1] = bx1; o[2] = by1; o[3] = bx2; o[4] = by2;
            atomicAnd(&sh.n.alive[i >> 5], ~(1u << (i & 31)));
        }
        for (int j = i + 1 + tid; j < PRE; j += 1024) {
            float x1 = sh.n.boxes[j][0], y1 = sh.n.boxes[j][1];
            float x2 = sh.n.boxes[j][2], y2 = sh.n.boxes[j][3];
            float xx1 = fmaxf(x1, bx1), yy1 = fmaxf(y1, by1);
            float xx2 = fminf(x2, bx2), yy2 = fminf(y2, by2);
            float iw = fmaxf(__fadd_rn(__fsub_rn(xx2, xx1), 1.0f), 0.f);
            float ih = fmaxf(__fadd_rn(__fsub_rn(yy2, yy1), 1.0f), 0.f);
            float inter = __fmul_rn(iw, ih);
            float denom = __fsub_rn(__fadd_rn(sh.n.areas[j], bar), inter);
            float iou = __fdiv_rn(inter, denom);
            if (iou > 0.7f) atomicAnd(&sh.n.alive[j >> 5], ~(1u << (j & 31)));
        }
        kept++;
        __syncthreads();
    }
}

// ---------------- launcher -----------------------------------------------------
extern "C" void kernel_launch(void* const* d_in, const int* in_sizes, int n_in,
                              void* d_out, int out_size, void* d_ws, size_t ws_size,
                              hipStream_t stream) {
    const float* probs    = (const float*)d_in[0];
    const float* deltas   = (const float*)d_in[1];
    const float* img_info = (const float*)d_in[2];
    float* out = (float*)d_out;

    char* ws = (char*)d_ws;
    size_t off = 0;
    u32* cntp = (u32*)(ws + off); off += (size_t)NB * 64 * sizeof(u32);
    u32* flag = (u32*)(ws + off); off += (size_t)NB * 64 * sizeof(u32);
    u32* thr  = (u32*)(ws + off); off += 4096;
    u32* hist = (u32*)(ws + off); off += (size_t)NB * 65536 * sizeof(u32);
    u64* cand = (u64*)(ws + off); off += (size_t)NB * CAP * sizeof(u64);
    u32* rank4 = (u32*)(ws + off); off += (size_t)NB * 4 * CAP * sizeof(u32);  // 2 MiB
    float4* gBoxes = (float4*)(ws + off); off += (size_t)NB * BOXSTRIDE * sizeof(float4);
    float*  gAreas = (float*)(ws + off);  off += (size_t)NB * BOXSTRIDE * sizeof(float);
    size_t tier1 = off;
    u32* maskC = (u32*)(ws + off); off += (size_t)NB * NSEG * MROWS2 * 8 * sizeof(u32); // 75.5 MiB
    size_t tier2 = off;

    dim3 gA((NA + 255) / 256, NB);

    if (ws_size >= tier1) {
        hipMemsetAsync(cntp, 0, (size_t)NB * 64 * sizeof(u32), stream);
        compact_fixed<<<gA, 256, 0, stream>>>(probs, cntp, cand);
        check_kernel<<<1, 64, 0, stream>>>(cntp, flag);
        zero_hist<<<dim3(256, NB), 256, 0, stream>>>(flag, hist);
        hist_kernel<<<gA, 256, 0, stream>>>(flag, probs, hist);
        thresh_kernel<<<NB, 1024, 0, stream>>>(flag, hist, thr);
        compact2_kernel<<<gA, 256, 0, stream>>>(flag, probs, thr, cntp, cand);
        rank_kernel<<<dim3(CAP / 256, 4, NB), 256, 0, stream>>>(cand, cntp, rank4);
        scatter_decode<<<dim3(CAP / 256, NB), 256, 0, stream>>>(cand, cntp, rank4, deltas,
                                                                img_info, gBoxes, gAreas, out);
        if (ws_size >= tier2) {
            mask_kernel<<<dim3(300, NB), 256, 0, stream>>>(gBoxes, gAreas, maskC);
            nms_scan<<<NB, 1024, 0, stream>>>(maskC, gBoxes, out);
        } else {
            nms_fused<<<NB, 1024, 0, stream>>>(gBoxes, gAreas, out);
        }
    } else {
        hipMemsetAsync(cntp, 0, (size_t)NB * 64 * sizeof(u32), stream);
        hipMemsetAsync(flag, 1, (size_t)NB * 64 * sizeof(u32), stream);
        hipMemsetAsync(hist, 0, (size_t)NB * 65536 * sizeof(u32), stream);
        hist_kernel<<<gA, 256, 0, stream>>>(flag, probs, hist);
        thresh_kernel<<<NB, 1024, 0, stream>>>(flag, hist, thr);
        compact2_kernel<<<gA, 256, 0, stream>>>(flag, probs, thr, cntp, cand);
        final_kernel<<<NB, 1024, 0, stream>>>(cand, cntp, deltas, img_info, out);
    }
}

// Round 21
// 400.747 us; speedup vs baseline: 1.0497x; 1.0497x over previous
//
#include <hip/hip_runtime.h>

#define NB 16
#define NA 261888
#define PRE 6000
#define POST 1000
#define CAP 8192
#define SEG 256
#define NSEG ((PRE + SEG - 1) / SEG)   // 24
#define BOXSTRIDE 6144
#define MROWS2 6144                    // mask rows per chunk (covers seg 23 diag)
#define KPAD 1024
#define CCHUNK 2048                    // rank col-split width (4 chunks over CAP)
#define THRF 0.972f
// Exact NMS predicate: RN32(inter/denom) > 0.7f  <=>  inter >= M*denom with
// M = midpoint(0.7f, nextafterf) = 0x1.666667p-1 (25-bit mantissa).
// f32-only form: fmaf(0.7f, denom, -inter) <= -2^-25*denom. Exact because
// M*denom - inter lies on a lattice of spacing 2^(ed-48) while the RN hazard
// band around -T is 2^(ed-49); equality (e==-T) included on both sides.

typedef unsigned int u32;
typedef unsigned long long u64;

__device__ __constant__ int NE_UNITS[10] = {0, 1, 2, 3, 5, 6, 7, 10, 11, 15};
__device__ __constant__ int TILE_N[3] = {4, 3, 3};
__device__ __constant__ int TILE_U[3][4] = {{0, 5, 10, 15}, {1, 2, 6, 0}, {3, 7, 11, 0}};

__device__ inline float box_area(float4 v) {
    return __fmul_rn(__fadd_rn(__fsub_rn(v.z, v.x), 1.0f),
                     __fadd_rn(__fsub_rn(v.w, v.y), 1.0f));
}

__device__ inline bool iou_supp(float4 a, float aa, float4 c, float ca) {
    float xx1 = fmaxf(c.x, a.x);
    float yy1 = fmaxf(c.y, a.y);
    float xx2 = fminf(c.z, a.z);
    float yy2 = fminf(c.w, a.w);
    float iw = fmaxf(__fadd_rn(__fsub_rn(xx2, xx1), 1.0f), 0.f);
    float ih = fmaxf(__fadd_rn(__fsub_rn(yy2, yy1), 1.0f), 0.f);
    float inter = __fmul_rn(iw, ih);
    float denom = __fsub_rn(__fadd_rn(ca, aa), inter);
    return __fmaf_rn(0.7f, denom, -inter) <= __fmul_rn(denom, -0x1p-25f);
}

// ---------------- anchors (match numpy float64 -> float32 exactly) -------------
__device__ inline void anchor_at(int idx, float& a0, float& a1, float& a2, float& a3) {
    int base, fw, stride, scale;
    if (idx < 196608)      { base = 0;      fw = 256; stride = 4;  scale = 4; }
    else if (idx < 245760) { base = 196608; fw = 128; stride = 8;  scale = 8; }
    else if (idx < 258048) { base = 245760; fw = 64;  stride = 16; scale = 16; }
    else if (idx < 261120) { base = 258048; fw = 32;  stride = 32; scale = 32; }
    else                   { base = 261120; fw = 16;  stride = 64; scale = 64; }
    int rel  = idx - base;
    int ri   = rel % 3;
    int cell = rel / 3;
    int col  = cell & (fw - 1);
    int row  = cell / fw;
    double cx = (col + 0.5) * (double)stride;
    double cy = (row + 0.5) * (double)stride;
    double sz = (double)scale * 8.0;
    double sq = (ri == 0) ? 0.7071067811865476 : ((ri == 1) ? 1.0 : 1.4142135623730951);
    double wsd = sz * sq;
    double hsd = sz / sq;
    a0 = (float)(cx - 0.5 * wsd);
    a1 = (float)(cy - 0.5 * hsd);
    a2 = (float)(cx + 0.5 * wsd);
    a3 = (float)(cy + 0.5 * hsd);
}

__device__ inline float4 decode_box(u64 key, int b, const float* __restrict__ deltas,
                                    float hmax, float wmax) {
    int a = (int)(~(u32)key);
    float a0, a1, a2, a3;
    anchor_at(a, a0, a1, a2, a3);
    const float4 d4 = *(const float4*)(deltas + ((size_t)b * NA + a) * 4);
    float w  = __fadd_rn(__fsub_rn(a2, a0), 1.0f);
    float h  = __fadd_rn(__fsub_rn(a3, a1), 1.0f);
    float cx = __fadd_rn(a0, __fmul_rn(0.5f, w));
    float cy = __fadd_rn(a1, __fmul_rn(0.5f, h));
    float pcx = __fadd_rn(__fmul_rn(d4.x, w), cx);
    float pcy = __fadd_rn(__fmul_rn(d4.y, h), cy);
    float pw  = __fmul_rn((float)exp((double)d4.z), w);
    float ph  = __fmul_rn((float)exp((double)d4.w), h);
    float x1 = __fsub_rn(pcx, __fmul_rn(0.5f, pw));
    float y1 = __fsub_rn(pcy, __fmul_rn(0.5f, ph));
    float x2 = __fadd_rn(pcx, __fmul_rn(0.5f, pw));
    float y2 = __fadd_rn(pcy, __fmul_rn(0.5f, ph));
    x1 = fminf(fmaxf(x1, 0.f), wmax);
    x2 = fminf(fmaxf(x2, 0.f), wmax);
    y1 = fminf(fmaxf(y1, 0.f), hmax);
    y2 = fminf(fmaxf(y2, 0.f), hmax);
    return make_float4(x1, y1, x2, y2);
}

// ---------------- fast path: fixed-threshold compact, block-aggregated ---------
__global__ void compact_fixed(const float* __restrict__ probs, u32* __restrict__ cntp,
                              u64* __restrict__ cand) {
    __shared__ u32 lcnt;
    __shared__ u32 lbase;
    int tid = threadIdx.x;
    int a = blockIdx.x * 256 + tid;
    int b = blockIdx.y;
    if (tid == 0) lcnt = 0;
    __syncthreads();
    float2 pv = *(const float2*)(probs + ((size_t)b * NA + a) * 2);
    float s = pv.y;
    u32 bits = __float_as_uint(s);
    int lpos = -1;
    if (s >= THRF) lpos = (int)atomicAdd(&lcnt, 1u);
    __syncthreads();
    if (tid == 0) lbase = lcnt ? atomicAdd(&cntp[b * 64], lcnt) : 0u;
    __syncthreads();
    if (lpos >= 0) {
        u32 pos = lbase + (u32)lpos;
        if (pos < CAP)
            cand[(size_t)b * CAP + pos] = ((u64)bits << 32) | (u32)(~(u32)a);
    }
}

// ---------------- validate fast path; set per-batch fallback flags -------------
__global__ void check_kernel(u32* __restrict__ cntp, u32* __restrict__ flag) {
    int t = threadIdx.x;
    if (t < NB) {
        u32 c = cntp[t * 64];
        u32 bad = (c < (u32)PRE || c > (u32)CAP) ? 1u : 0u;
        flag[t * 64] = bad;
        if (bad) cntp[t * 64] = 0;
    }
}

// ---------------- gated fallback: zero hist ------------------------------------
__global__ void zero_hist(const u32* __restrict__ flag, u32* __restrict__ hist) {
    int b = blockIdx.y;
    if (flag[b * 64] == 0) return;
    int i = blockIdx.x * 256 + threadIdx.x;
    hist[(size_t)b * 65536 + i] = 0;
}

// ---------------- gated fallback: histogram ------------------------------------
__global__ void hist_kernel(const u32* __restrict__ flag, const float* __restrict__ probs,
                            u32* __restrict__ hist) {
    int b = blockIdx.y;
    if (flag[b * 64] == 0) return;
    int a = blockIdx.x * 256 + threadIdx.x;
    float2 pv = *(const float2*)(probs + ((size_t)b * NA + a) * 2);
    u32 bits = __float_as_uint(pv.y);
    atomicAdd(&hist[(size_t)b * 65536 + (bits >> 16)], 1u);
}

// ---------------- gated fallback: per-batch threshold --------------------------
__global__ __launch_bounds__(1024) void thresh_kernel(const u32* __restrict__ flag,
                                                      const u32* __restrict__ hist,
                                                      u32* __restrict__ thr) {
    int b = blockIdx.x;
    if (flag[b * 64] == 0) return;
    __shared__ u32 csum[1024];
    int t = threadIdx.x;
    const u32* h = hist + (size_t)b * 65536;
    u32 s = 0;
    for (int k = 0; k < 64; k++) s += h[t * 64 + k];
    csum[t] = s;
    __syncthreads();
    if (t == 0) {
        u32 cum = 0;
        int bucket = 0;
        for (int c = 1023; c >= 0; c--) {
            if (cum + csum[c] >= (u32)PRE) {
                u32 cum2 = cum;
                for (int k = 63; k >= 0; k--) {
                    cum2 += h[c * 64 + k];
                    if (cum2 >= (u32)PRE) { bucket = c * 64 + k; break; }
                }
                break;
            }
            cum += csum[c];
        }
        thr[b] = (u32)bucket << 16;
    }
}

// ---------------- gated fallback: compact with exact threshold -----------------
__global__ void compact2_kernel(const u32* __restrict__ flag, const float* __restrict__ probs,
                                const u32* __restrict__ thr, u32* __restrict__ cntp,
                                u64* __restrict__ cand) {
    int b = blockIdx.y;
    if (flag[b * 64] == 0) return;
    __shared__ u32 lcnt;
    __shared__ u32 lbase;
    int tid = threadIdx.x;
    int a = blockIdx.x * 256 + tid;
    if (tid == 0) lcnt = 0;
    __syncthreads();
    float2 pv = *(const float2*)(probs + ((size_t)b * NA + a) * 2);
    u32 bits = __float_as_uint(pv.y);
    int lpos = -1;
    if (bits >= thr[b]) lpos = (int)atomicAdd(&lcnt, 1u);
    __syncthreads();
    if (tid == 0) lbase = lcnt ? atomicAdd(&cntp[b * 64], lcnt) : 0u;
    __syncthreads();
    if (lpos >= 0) {
        u32 pos = lbase + (u32)lpos;
        if (pos < CAP)
            cand[(size_t)b * CAP + pos] = ((u64)bits << 32) | (u32)(~(u32)a);
    }
}

// ---------------- all-pairs rank, 4-way column-split (full occupancy) ----------
__global__ __launch_bounds__(256) void rank_kernel(const u64* __restrict__ cand,
                                                   const u32* __restrict__ cntp,
                                                   u32* __restrict__ rank4) {
    __shared__ u64 ckey[256];
    int rt = blockIdx.x;
    int cchunk = blockIdx.y;
    int b = blockIdx.z;
    int cnt = (int)min(cntp[b * 64], (u32)CAP);
    int t = threadIdx.x;
    const u64* cb = cand + (size_t)b * CAP;
    int row = rt * 256 + t;
    u64 rkey = (row < cnt) ? cb[row] : ~0ULL;
    u32 acc = 0;
    int c0 = cchunk * CCHUNK;
    int c1 = c0 + CCHUNK; if (c1 > cnt) c1 = cnt;
    for (int cc0 = c0; cc0 < c1; cc0 += 256) {
        __syncthreads();
        int ci = cc0 + t;
        ckey[t] = (ci < c1) ? cb[ci] : 0ULL;   // key 0 < any valid key -> contributes 0
        __syncthreads();
        int lim = c1 - cc0; if (lim > 256) lim = 256;
        int c = 0;
        for (; c + 4 <= lim; c += 4) {
            u64 k0 = ckey[c], k1 = ckey[c + 1], k2 = ckey[c + 2], k3 = ckey[c + 3];
            acc += (k0 > rkey) ? 1u : 0u;
            acc += (k1 > rkey) ? 1u : 0u;
            acc += (k2 > rkey) ? 1u : 0u;
            acc += (k3 > rkey) ? 1u : 0u;
        }
        for (; c < lim; ++c) acc += (ckey[c] > rkey) ? 1u : 0u;
    }
    rank4[(((size_t)b * 4 + cchunk) * CAP) + row] = acc;
}

// ---------------- scatter decode: gBoxes[rank[i]] = decode(cand[i]) ------------
__global__ void scatter_decode(const u64* __restrict__ cand, const u32* __restrict__ cntp,
                               const u32* __restrict__ rank4, const float* __restrict__ deltas,
                               const float* __restrict__ img_info, float4* __restrict__ gBoxes,
                               float* __restrict__ gAreas, float* __restrict__ out) {
    int i = blockIdx.x * 256 + threadIdx.x;     // 0..8191
    int b = blockIdx.y;
    if (i < POST) {
        float* o = out + ((size_t)b * POST + i) * 5;
        o[0] = (float)b; o[1] = 0.f; o[2] = 0.f; o[3] = 0.f; o[4] = 0.f;
    }
    int cnt = (int)min(cntp[b * 64], (u32)CAP);
    if (i >= cnt) return;
    u32 r = rank4[(((size_t)b * 4 + 0) * CAP) + i]
          + rank4[(((size_t)b * 4 + 1) * CAP) + i]
          + rank4[(((size_t)b * 4 + 2) * CAP) + i]
          + rank4[(((size_t)b * 4 + 3) * CAP) + i];
    if (r >= (u32)BOXSTRIDE) return;
    float hmax = __fsub_rn(img_info[b * 3 + 0], 1.0f);
    float wmax = __fsub_rn(img_info[b * 3 + 1], 1.0f);
    float4 bx = decode_box(cand[(size_t)b * CAP + i], b, deltas, hmax, wmax);
    gBoxes[(size_t)b * BOXSTRIDE + r] = bx;
    gAreas[(size_t)b * BOXSTRIDE + r] = box_area(bx);
}

// ---------------- full suppression bitmask (R19 structure + pad-only fix) ------
__global__ __launch_bounds__(256) void mask_kernel(const float4* __restrict__ gBoxes,
                                                   const float* __restrict__ gAreas,
                                                   u32* __restrict__ maskC) {
    __shared__ float4 cbox[256];
    __shared__ float  carea[256];
    __shared__ u32    tileOut[256][9];          // pad 8->9: conflict-free stores
    int lin = blockIdx.x;          // 0..299 over (rt, cc), cc >= rt
    int b = blockIdx.y;
    int rt = 0, rem = lin;
    while (rem >= NSEG - rt) { rem -= NSEG - rt; ++rt; }
    int cc = rt + rem;
    int t = threadIdx.x;
    int l = t & 63, q = t >> 6;
    const float4* gb = gBoxes + (size_t)b * BOXSTRIDE;
    const float*  ga = gAreas + (size_t)b * BOXSTRIDE;
    cbox[t] = gb[cc * 256 + t];
    carea[t] = ga[cc * 256 + t];
    float4 rb[4]; float ra[4]; int gr[4];
    #pragma unroll
    for (int j = 0; j < 4; ++j) {
        gr[j] = rt * 256 + l + 64 * j;
        rb[j] = gb[gr[j]];
        ra[j] = ga[gr[j]];
    }
    __syncthreads();
    int colbase = cc * 256 + q * 64;
    u32 a0[4] = {0u, 0u, 0u, 0u};
    u32 a1[4] = {0u, 0u, 0u, 0u};
    for (int c = 0; c < 32; ++c) {
        float4 cbx = cbox[q * 64 + c];        // wave-uniform -> broadcast
        float  cav = carea[q * 64 + c];
        int gc = colbase + c;
        #pragma unroll
        for (int j = 0; j < 4; ++j) {
            bool bit = (gc > gr[j]) && iou_supp(rb[j], ra[j], cbx, cav);
            a0[j] |= (bit ? 1u : 0u) << c;
        }
    }
    for (int c = 0; c < 32; ++c) {
        float4 cbx = cbox[q * 64 + 32 + c];
        float  cav = carea[q * 64 + 32 + c];
        int gc = colbase + 32 + c;
        #pragma unroll
        for (int j = 0; j < 4; ++j) {
            bool bit = (gc > gr[j]) && iou_supp(rb[j], ra[j], cbx, cav);
            a1[j] |= (bit ? 1u : 0u) << c;
        }
    }
    #pragma unroll
    for (int j = 0; j < 4; ++j) {
        tileOut[l + 64 * j][2 * q]     = a0[j];
        tileOut[l + 64 * j][2 * q + 1] = a1[j];
    }
    __syncthreads();
    uint4* rec = (uint4*)(maskC + (((size_t)b * NSEG + cc) * MROWS2 + rt * 256 + t) * 8);
    rec[0] = make_uint4(tileOut[t][0], tileOut[t][1], tileOut[t][2], tileOut[t][3]);
    rec[1] = make_uint4(tileOut[t][4], tileOut[t][5], tileOut[t][6], tileOut[t][7]);
}

// ---------------- pipelined mask-driven greedy NMS scan ------------------------
__global__ __launch_bounds__(1024) void nms_scan(const u32* __restrict__ maskC,
                                                 const float4* __restrict__ gBoxes,
                                                 float* __restrict__ out) {
    __shared__ u32 tile[2][SEG][8];
    __shared__ u32 aliveC[2][8];
    __shared__ u32 accW[2][8];
    __shared__ int keptList[POST];
    __shared__ int Kvar;

    int b = blockIdx.x;
    int t = threadIdx.x;
    int lane = t & 63;
    int w = t >> 6;
    const u32* mb = maskC + (size_t)b * NSEG * MROWS2 * 8;

    if (t < 8) {
        aliveC[0][t] = 0xFFFFFFFFu;
        accW[0][t] = 0u;
    } else if (t < 16) {
        accW[1][t - 8] = 0u;
    }
    if (t == 0) Kvar = 0;
    {   // prefetch tile 0
        const uint4* src = (const uint4*)mb;
        uint4* dst = (uint4*)&tile[0][0][0];
        for (int i = t; i < SEG * 2; i += 1024) dst[i] = src[i];
    }

    for (int s = 0; s < NSEG; ++s) {
        int bufc = s & 1, bufn = bufc ^ 1;
        __syncthreads();                    // barrier A
        int Kpre = Kvar;
        if (Kpre >= POST) break;            // uniform

        if (w == 0) {
            // ---- serial greedy scan of segment s (wave 0)
            u32 va = (lane < 8) ? aliveC[bufc][lane] : 0u;
            int KK = Kpre;
            while (true) {
                u64 balv = __ballot(va != 0u);
                if (balv == 0ULL) break;
                int wsel = __ffsll(balv) - 1;
                u32 word = __builtin_amdgcn_readlane(va, wsel);
                int r = (wsel << 5) + (__ffs(word) - 1);
                u32 trow = tile[bufc][r][lane & 7];
                if (lane == 8) keptList[KK] = s * SEG + r;
                u32 self = (lane == (r >> 5)) ? (1u << (r & 31)) : 0u;
                if (lane < 8) va &= ~(trow | self);
                ++KK;
                if (KK == POST) break;
            }
            if (lane == 0) Kvar = KK;
        } else if (s + 1 < NSEG) {
            // ---- bulk apply for chunk s+1: kepts [0, Kpre), 120 threads/word
            const u32* mbC = mb + (size_t)(s + 1) * (MROWS2 * 8);
            int wi = t & 7;
            int sub = (t - 64) >> 3;        // 0..119
            u32 part = 0;
            int j = sub;
            for (; j + 480 < Kpre; j += 480) {
                u32 x0 = mbC[(size_t)keptList[j] * 8 + wi];
                u32 x1 = mbC[(size_t)keptList[j + 120] * 8 + wi];
                u32 x2 = mbC[(size_t)keptList[j + 240] * 8 + wi];
                u32 x3 = mbC[(size_t)keptList[j + 360] * 8 + wi];
                part |= x0 | x1 | x2 | x3;
            }
            for (; j < Kpre; j += 120)
                part |= mbC[(size_t)keptList[j] * 8 + wi];
            if (part) atomicOr(&accW[bufn][wi], part);
            // ---- tile prefetch s+1 (8KB)
            const uint4* src = (const uint4*)(mbC + (size_t)(s + 1) * SEG * 8);
            uint4* dst = (uint4*)&tile[bufn][0][0];
            for (int i = t - 64; i < SEG * 2; i += 960) dst[i] = src[i];
        }
        __syncthreads();                    // barrier B

        int Kcur = Kvar;
        if (s + 1 < NSEG) {
            // ---- residual apply: delta kepts from scan(s)
            const u32* mbC = mb + (size_t)(s + 1) * (MROWS2 * 8);
            int delta8 = (Kcur - Kpre) * 8;
            for (int idx = t; idx < delta8; idx += 1024) {
                int j = Kpre + (idx >> 3);
                int wi = idx & 7;
                u32 x = mbC[(size_t)keptList[j] * 8 + wi];
                if (x) atomicOr(&accW[bufn][wi], x);
            }
        }
        __syncthreads();                    // barrier C

        if (s + 1 < NSEG) {
            if (t < 8) {
                int W = (s + 1) * 8 + t;
                u32 init = (W < 187) ? 0xFFFFFFFFu : ((W == 187) ? 0xFFFFu : 0u);
                aliveC[bufn][t] = init & ~accW[bufn][t];
            } else if (t < 16) {
                accW[bufc][t - 8] = 0u;     // recycle for chunk s+2
            }
        }
    }
    __syncthreads();

    int K = Kvar;
    const float4* gb = gBoxes + (size_t)b * BOXSTRIDE;
    for (int i = t; i < K; i += 1024) {
        int j = keptList[i];
        float4 bx = gb[j];
        float* o = out + ((size_t)b * POST + i) * 5;
        o[0] = (float)b; o[1] = bx.x; o[2] = bx.y; o[3] = bx.z; o[4] = bx.w;
    }
}

// ---------------- mid-ws tier: R14 pipelined fused lazy NMS --------------------
__global__ __launch_bounds__(1024) void nms_fused(const float4* __restrict__ gBoxes,
                                                  const float* __restrict__ gAreas,
                                                  float* __restrict__ out) {
    __shared__ float4 segBox[2][SEG];
    __shared__ float  segArea[2][SEG];
    __shared__ u32    tile[2][SEG][8];
    __shared__ u32    aliveW[2][8];
    __shared__ unsigned char aliveB[3][SEG];
    __shared__ float4 keptBox[KPAD];
    __shared__ float  keptArea[KPAD];
    __shared__ int    Kvar;

    int b = blockIdx.x;
    int t = threadIdx.x;
    int lane = t & 63;
    int w = t >> 6;
    if (t == 0) Kvar = 0;
    const float4* gb = gBoxes + (size_t)b * BOXSTRIDE;
    const float*  ga = gAreas + (size_t)b * BOXSTRIDE;

    if (t < SEG) {
        segBox[0][t] = gb[t];
        segArea[0][t] = ga[t];
    }
    __syncthreads();
    if (w < 10) {
        int u = NE_UNITS[w];
        int wc = u & 3, h = u >> 2;
        int c = wc * 64 + lane;
        float4 cb = segBox[0][c];
        float  ca = segArea[0][c];
        for (int r = h * 64; r < h * 64 + 64; ++r) {
            float4 rb = segBox[0][r];
            float  ra = segArea[0][r];
            bool bit = (r < c) && iou_supp(rb, ra, cb, ca);
            u64 bal = __ballot(bit);
            if (lane == 0) tile[0][r][2 * wc]     = (u32)bal;
            if (lane == 1) tile[0][r][2 * wc + 1] = (u32)(bal >> 32);
        }
    }
    if (t < SEG) {
        u64 bal = __ballot(true);
        if (lane == 0) aliveW[0][2 * w]     = (u32)bal;
        if (lane == 1) aliveW[0][2 * w + 1] = (u32)(bal >> 32);
    }

    int Kprev = 0;
    for (int s = 0; s < NSEG; ++s) {
        int bufc = s & 1, bufn = bufc ^ 1;
        __syncthreads();
        int Kcur = Kvar;
        if (Kcur >= POST) break;

        if (t < SEG) {
            if (s > 0) {
                bool al = aliveB[0][t] && aliveB[1][t] && aliveB[2][t];
                if (al && Kcur > Kprev) {
                    float4 rb = segBox[bufc][t];
                    float  ra = segArea[bufc][t];
                    int k = Kprev;
                    while (k < Kcur) {
                        bool d0 = iou_supp(keptBox[k], keptArea[k], rb, ra);
                        bool d1 = ((k + 1) < Kcur) & iou_supp(keptBox[k + 1], keptArea[k + 1], rb, ra);
                        bool d2 = ((k + 2) < Kcur) & iou_supp(keptBox[k + 2], keptArea[k + 2], rb, ra);
                        bool d3 = ((k + 3) < Kcur) & iou_supp(keptBox[k + 3], keptArea[k + 3], rb, ra);
                        if (d0 | d1 | d2 | d3) { al = false; break; }
                        k += 4;
                    }
                }
                u64 bal = __ballot(al);
                if (lane == 0) aliveW[bufc][2 * w]     = (u32)bal;
                if (lane == 1) aliveW[bufc][2 * w + 1] = (u32)(bal >> 32);
            }
            if (s + 1 < NSEG) {
                int g = (s + 1) * SEG + t;
                segBox[bufn][t] = gb[g];
                segArea[bufn][t] = ga[g];
                unsigned char v8 = (g < PRE) ? 1 : 0;
                aliveB[0][t] = v8; aliveB[1][t] = v8; aliveB[2][t] = v8;
            }
        }
        __syncthreads();

        if (w == 0) {
            int l = lane;
            u32 va = (l < 8) ? aliveW[bufc][l] : 0u;
            int KK = Kcur;
            while (true) {
                u64 balv = __ballot(va != 0u);
                if (balv == 0ULL) break;
                int wsel = __ffsll(balv) - 1;
                u32 word = __builtin_amdgcn_readlane(va, wsel);
                int r = (wsel << 5) + (__ffs(word) - 1);
                u32 trow = tile[bufc][r][l & 7];
                if (l >= 8 && l < 12)
                    ((float*)keptBox)[KK * 4 + (l - 8)] = ((const float*)segBox[bufc])[r * 4 + (l - 8)];
                if (l == 12) keptArea[KK] = segArea[bufc][r];
                u32 self = (l == (r >> 5)) ? (1u << (r & 31)) : 0u;
                if (l < 8) va &= ~(trow | self);
                ++KK;
                if (KK == POST) break;
            }
            if (l == 0) Kvar = KK;
        } else if (w <= 12) {
            if (s + 1 < NSEG && Kcur > 0) {
                int ww = w - 1;
                int rg = ww & 3;
                int kc = ww >> 2;
                int row = rg * 64 + lane;
                float4 rb = segBox[bufn][row];
                float  ra = segArea[bufn][row];
                bool dead = false, written = false;
                int q = 0;
                int k = kc;
                while (k < Kcur) {
                    int k1 = k + 3, k2 = k + 6, k3 = k + 9;
                    bool d0 = iou_supp(keptBox[k], keptArea[k], rb, ra);
                    bool d1 = (k1 < Kcur) & iou_supp(keptBox[k1], keptArea[k1], rb, ra);
                    bool d2 = (k2 < Kcur) & iou_supp(keptBox[k2], keptArea[k2], rb, ra);
                    bool d3 = (k3 < Kcur) & iou_supp(keptBox[k3], keptArea[k3], rb, ra);
                    dead |= (d0 | d1 | d2 | d3);
                    k += 12;
                    if (((++q) & 7) == 0) {
                        if (dead && !written) { aliveB[kc][row] = 0; written = true; }
                        u32 comb = (u32)aliveB[0][row] & (u32)aliveB[1][row] & (u32)aliveB[2][row];
                        if (__ballot(comb != 0u) == 0ULL) break;
                    }
                }
                if (dead && !written) aliveB[kc][row] = 0;
            }
        } else {
            if (s + 1 < NSEG) {
                int g3 = w - 13;
                int nu = TILE_N[g3];
                for (int ui = 0; ui < nu; ++ui) {
                    int u = TILE_U[g3][ui];
                    int wc = u & 3, h = u >> 2;
                    int c = wc * 64 + lane;
                    float4 cb = segBox[bufn][c];
                    float  ca = segArea[bufn][c];
                    for (int r = h * 64; r < h * 64 + 64; ++r) {
                        float4 rb = segBox[bufn][r];
                        float  ra = segArea[bufn][r];
                        bool bit = (r < c) && iou_supp(rb, ra, cb, ca);
                        u64 bal = __ballot(bit);
                        if (lane == 0) tile[bufn][r][2 * wc]     = (u32)bal;
                        if (lane == 1) tile[bufn][r][2 * wc + 1] = (u32)(bal >> 32);
                    }
                }
            }
        }
        Kprev = Kcur;
    }
    __syncthreads();

    int K = Kvar;
    for (int s2 = t; s2 < POST; s2 += 1024) {
        float* o = out + ((size_t)b * POST + s2) * 5;
        if (s2 < K) {
            float4 bx = keptBox[s2];
            o[0] = (float)b; o[1] = bx.x; o[2] = bx.y; o[3] = bx.z; o[4] = bx.w;
        } else {
            o[0] = (float)b; o[1] = 0.f; o[2] = 0.f; o[3] = 0.f; o[4] = 0.f;
        }
    }
}

// ---------------- fallback: monolithic sort+decode+NMS (small ws) --------------
__global__ __launch_bounds__(1024) void final_kernel(const u64* __restrict__ cand, const u32* __restrict__ cntp,
                             const float* __restrict__ deltas, const float* __restrict__ img_info,
                             float* __restrict__ out) {
    __shared__ union {
        u64 keys[CAP];
        struct {
            float boxes[PRE][4];
            float areas[PRE];
            u32   alive[192];
        } n;
    } sh;
    __shared__ int s_next;

    int b = blockIdx.x;
    int tid = threadIdx.x;

    for (int s = tid; s < POST; s += 1024) {
        float* o = out + ((size_t)b * POST + s) * 5;
        o[0] = (float)b; o[1] = 0.f; o[2] = 0.f; o[3] = 0.f; o[4] = 0.f;
    }

    int n = (int)min(cntp[b * 64], (u32)CAP);
    for (int i = tid; i < CAP; i += 1024)
        sh.keys[i] = (i < n) ? cand[(size_t)b * CAP + i] : 0ULL;
    __syncthreads();

    for (int k = 2; k <= CAP; k <<= 1) {
        for (int j = k >> 1; j > 0; j >>= 1) {
            for (int i = tid; i < CAP; i += 1024) {
                int ixj = i ^ j;
                if (ixj > i) {
                    u64 x = sh.keys[i], y = sh.keys[ixj];
                    bool desc = ((i & k) == 0);
                    if (desc ? (x < y) : (x > y)) { sh.keys[i] = y; sh.keys[ixj] = x; }
                }
            }
            __syncthreads();
        }
    }

    u32 myIdx[6];
    #pragma unroll
    for (int r = 0; r < 6; r++) {
        int i = tid + r * 1024;
        if (i < PRE) myIdx[r] = ~(u32)(sh.keys[i]);
    }
    __syncthreads();

    float hmax = __fsub_rn(img_info[b * 3 + 0], 1.0f);
    float wmax = __fsub_rn(img_info[b * 3 + 1], 1.0f);

    #pragma unroll
    for (int r = 0; r < 6; r++) {
        int i = tid + r * 1024;
        if (i < PRE) {
            int a = (int)myIdx[r];
            float a0, a1, a2, a3;
            anchor_at(a, a0, a1, a2, a3);
            const float4 d4 = *(const float4*)(deltas + ((size_t)b * NA + a) * 4);
            float w  = __fadd_rn(__fsub_rn(a2, a0), 1.0f);
            float h  = __fadd_rn(__fsub_rn(a3, a1), 1.0f);
            float cx = __fadd_rn(a0, __fmul_rn(0.5f, w));
            float cy = __fadd_rn(a1, __fmul_rn(0.5f, h));
            float pcx = __fadd_rn(__fmul_rn(d4.x, w), cx);
            float pcy = __fadd_rn(__fmul_rn(d4.y, h), cy);
            float pw  = __fmul_rn((float)exp((double)d4.z), w);
            float ph  = __fmul_rn((float)exp((double)d4.w), h);
            float x1 = __fsub_rn(pcx, __fmul_rn(0.5f, pw));
            float y1 = __fsub_rn(pcy, __fmul_rn(0.5f, ph));
            float x2 = __fadd_rn(pcx, __fmul_rn(0.5f, pw));
            float y2 = __fadd_rn(pcy, __fmul_rn(0.5f, ph));
            x1 = fminf(fmaxf(x1, 0.f), wmax);
            x2 = fminf(fmaxf(x2, 0.f), wmax);
            y1 = fminf(fmaxf(y1, 0.f), hmax);
            y2 = fminf(fmaxf(y2, 0.f), hmax);
            sh.n.boxes[i][0] = x1; sh.n.boxes[i][1] = y1;
            sh.n.boxes[i][2] = x2; sh.n.boxes[i][3] = y2;
            sh.n.areas[i] = __fmul_rn(__fadd_rn(__fsub_rn(x2, x1), 1.0f),
                                      __fadd_rn(__fsub_rn(y2, y1), 1.0f));
        }
    }

    for (int wdi = tid; wdi < 192; wdi += 1024) {
        u32 v = 0xFFFFFFFFu;
        if (wdi == 187) v = 0x0000FFFFu;
        if (wdi > 187)  v = 0u;
        sh.n.alive[wdi] = v;
    }
    __syncthreads();

    int kept = 0;
    int scanWord = 0;
    while (kept < POST) {
        if (tid == 0) {
            int found = -1;
            while (scanWord < 188) {
                u32 wv = sh.n.alive[scanWord];
                if (wv) { found = scanWord * 32 + (__ffs(wv) - 1); break; }
                scanWord++;
            }
            s_next = found;
        }
        __syncthreads();
        int i = s_next;
        if (i < 0) break;
        float bx1 = sh.n.boxes[i][0], by1 = sh.n.boxes[i][1];
        float bx2 = sh.n.boxes[i][2], by2 = sh.n.boxes[i][3];
        float bar = sh.n.areas[i];
        if (tid == 0) {
            float* o = out + ((size_t)b * POST + kept) * 5;
            o[1] = bx1; o[2] = by1; o[3] = bx2; o[4] = by2;
            atomicAnd(&sh.n.alive[i >> 5], ~(1u << (i & 31)));
        }
        for (int j = i + 1 + tid; j < PRE; j += 1024) {
            float x1 = sh.n.boxes[j][0], y1 = sh.n.boxes[j][1];
            float x2 = sh.n.boxes[j][2], y2 = sh.n.boxes[j][3];
            float xx1 = fmaxf(x1, bx1), yy1 = fmaxf(y1, by1);
            float xx2 = fminf(x2, bx2), yy2 = fminf(y2, by2);
            float iw = fmaxf(__fadd_rn(__fsub_rn(xx2, xx1), 1.0f), 0.f);
            float ih = fmaxf(__fadd_rn(__fsub_rn(yy2, yy1), 1.0f), 0.f);
            float inter = __fmul_rn(iw, ih);
            float denom = __fsub_rn(__fadd_rn(sh.n.areas[j], bar), inter);
            float iou = __fdiv_rn(inter, denom);
            if (iou > 0.7f) atomicAnd(&sh.n.alive[j >> 5], ~(1u << (j & 31)));
        }
        kept++;
        __syncthreads();
    }
}

// ---------------- launcher -----------------------------------------------------
extern "C" void kernel_launch(void* const* d_in, const int* in_sizes, int n_in,
                              void* d_out, int out_size, void* d_ws, size_t ws_size,
                              hipStream_t stream) {
    const float* probs    = (const float*)d_in[0];
    const float* deltas   = (const float*)d_in[1];
    const float* img_info = (const float*)d_in[2];
    float* out = (float*)d_out;

    char* ws = (char*)d_ws;
    size_t off = 0;
    u32* cntp = (u32*)(ws + off); off += (size_t)NB * 64 * sizeof(u32);
    u32* flag = (u32*)(ws + off); off += (size_t)NB * 64 * sizeof(u32);
    u32* thr  = (u32*)(ws + off); off += 4096;
    u32* hist = (u32*)(ws + off); off += (size_t)NB * 65536 * sizeof(u32);
    u64* cand = (u64*)(ws + off); off += (size_t)NB * CAP * sizeof(u64);
    u32* rank4 = (u32*)(ws + off); off += (size_t)NB * 4 * CAP * sizeof(u32);  // 2 MiB
    float4* gBoxes = (float4*)(ws + off); off += (size_t)NB * BOXSTRIDE * sizeof(float4);
    float*  gAreas = (float*)(ws + off);  off += (size_t)NB * BOXSTRIDE * sizeof(float);
    size_t tier1 = off;
    u32* maskC = (u32*)(ws + off); off += (size_t)NB * NSEG * MROWS2 * 8 * sizeof(u32); // 75.5 MiB
    size_t tier2 = off;

    dim3 gA((NA + 255) / 256, NB);

    if (ws_size >= tier1) {
        hipMemsetAsync(cntp, 0, (size_t)NB * 64 * sizeof(u32), stream);
        compact_fixed<<<gA, 256, 0, stream>>>(probs, cntp, cand);
        check_kernel<<<1, 64, 0, stream>>>(cntp, flag);
        zero_hist<<<dim3(256, NB), 256, 0, stream>>>(flag, hist);
        hist_kernel<<<gA, 256, 0, stream>>>(flag, probs, hist);
        thresh_kernel<<<NB, 1024, 0, stream>>>(flag, hist, thr);
        compact2_kernel<<<gA, 256, 0, stream>>>(flag, probs, thr, cntp, cand);
        rank_kernel<<<dim3(CAP / 256, 4, NB), 256, 0, stream>>>(cand, cntp, rank4);
        scatter_decode<<<dim3(CAP / 256, NB), 256, 0, stream>>>(cand, cntp, rank4, deltas,
                                                                img_info, gBoxes, gAreas, out);
        if (ws_size >= tier2) {
            mask_kernel<<<dim3(300, NB), 256, 0, stream>>>(gBoxes, gAreas, maskC);
            nms_scan<<<NB, 1024, 0, stream>>>(maskC, gBoxes, out);
        } else {
            nms_fused<<<NB, 1024, 0, stream>>>(gBoxes, gAreas, out);
        }
    } else {
        hipMemsetAsync(cntp, 0, (size_t)NB * 64 * sizeof(u32), stream);
        hipMemsetAsync(flag, 1, (size_t)NB * 64 * sizeof(u32), stream);
        hipMemsetAsync(hist, 0, (size_t)NB * 65536 * sizeof(u32), stream);
        hist_kernel<<<gA, 256, 0, stream>>>(flag, probs, hist);
        thresh_kernel<<<NB, 1024, 0, stream>>>(flag, hist, thr);
        compact2_kernel<<<gA, 256, 0, stream>>>(flag, probs, thr, cntp, cand);
        final_kernel<<<NB, 1024, 0, stream>>>(cand, cntp, deltas, img_info, out);
    }
}

// Round 22
// 364.243 us; speedup vs baseline: 1.1549x; 1.1002x over previous
//
#include <hip/hip_runtime.h>

#define NB 16
#define NA 261888
#define PRE 6000
#define POST 1000
#define CAP 8192
#define SEG 256
#define NSEG ((PRE + SEG - 1) / SEG)   // 24
#define BOXSTRIDE 6144
#define MROWS2 6144                    // mask rows per chunk (covers seg 23 diag)
#define KPAD 1024
#define CCHUNK 2048                    // rank col-split width (4 chunks over CAP)
#define THRF 0.972f
// Exact NMS predicate: RN32(inter/denom) > 0.7f  <=>  inter >= M*denom with
// M = midpoint(0.7f, nextafterf) = 0x1.666667p-1 (25-bit mantissa).
// f32-only form: fmaf(0.7f, denom, -inter) <= -2^-25*denom. Exact because
// M*denom - inter lies on a lattice of spacing 2^(ed-48) while the RN hazard
// band around -T is 2^(ed-49); equality (e==-T) included on both sides.

typedef unsigned int u32;
typedef unsigned long long u64;

__device__ __constant__ int NE_UNITS[10] = {0, 1, 2, 3, 5, 6, 7, 10, 11, 15};
__device__ __constant__ int TILE_N[3] = {4, 3, 3};
__device__ __constant__ int TILE_U[3][4] = {{0, 5, 10, 15}, {1, 2, 6, 0}, {3, 7, 11, 0}};

__device__ inline float box_area(float4 v) {
    return __fmul_rn(__fadd_rn(__fsub_rn(v.z, v.x), 1.0f),
                     __fadd_rn(__fsub_rn(v.w, v.y), 1.0f));
}

__device__ inline bool iou_supp(float4 a, float aa, float4 c, float ca) {
    float xx1 = fmaxf(c.x, a.x);
    float yy1 = fmaxf(c.y, a.y);
    float xx2 = fminf(c.z, a.z);
    float yy2 = fminf(c.w, a.w);
    float iw = fmaxf(__fadd_rn(__fsub_rn(xx2, xx1), 1.0f), 0.f);
    float ih = fmaxf(__fadd_rn(__fsub_rn(yy2, yy1), 1.0f), 0.f);
    float inter = __fmul_rn(iw, ih);
    float denom = __fsub_rn(__fadd_rn(ca, aa), inter);
    return __fmaf_rn(0.7f, denom, -inter) <= __fmul_rn(denom, -0x1p-25f);
}

// ---------------- anchors (match numpy float64 -> float32 exactly) -------------
__device__ inline void anchor_at(int idx, float& a0, float& a1, float& a2, float& a3) {
    int base, fw, stride, scale;
    if (idx < 196608)      { base = 0;      fw = 256; stride = 4;  scale = 4; }
    else if (idx < 245760) { base = 196608; fw = 128; stride = 8;  scale = 8; }
    else if (idx < 258048) { base = 245760; fw = 64;  stride = 16; scale = 16; }
    else if (idx < 261120) { base = 258048; fw = 32;  stride = 32; scale = 32; }
    else                   { base = 261120; fw = 16;  stride = 64; scale = 64; }
    int rel  = idx - base;
    int ri   = rel % 3;
    int cell = rel / 3;
    int col  = cell & (fw - 1);
    int row  = cell / fw;
    double cx = (col + 0.5) * (double)stride;
    double cy = (row + 0.5) * (double)stride;
    double sz = (double)scale * 8.0;
    double sq = (ri == 0) ? 0.7071067811865476 : ((ri == 1) ? 1.0 : 1.4142135623730951);
    double wsd = sz * sq;
    double hsd = sz / sq;
    a0 = (float)(cx - 0.5 * wsd);
    a1 = (float)(cy - 0.5 * hsd);
    a2 = (float)(cx + 0.5 * wsd);
    a3 = (float)(cy + 0.5 * hsd);
}

__device__ inline float4 decode_box(u64 key, int b, const float* __restrict__ deltas,
                                    float hmax, float wmax) {
    int a = (int)(~(u32)key);
    float a0, a1, a2, a3;
    anchor_at(a, a0, a1, a2, a3);
    const float4 d4 = *(const float4*)(deltas + ((size_t)b * NA + a) * 4);
    float w  = __fadd_rn(__fsub_rn(a2, a0), 1.0f);
    float h  = __fadd_rn(__fsub_rn(a3, a1), 1.0f);
    float cx = __fadd_rn(a0, __fmul_rn(0.5f, w));
    float cy = __fadd_rn(a1, __fmul_rn(0.5f, h));
    float pcx = __fadd_rn(__fmul_rn(d4.x, w), cx);
    float pcy = __fadd_rn(__fmul_rn(d4.y, h), cy);
    float pw  = __fmul_rn((float)exp((double)d4.z), w);
    float ph  = __fmul_rn((float)exp((double)d4.w), h);
    float x1 = __fsub_rn(pcx, __fmul_rn(0.5f, pw));
    float y1 = __fsub_rn(pcy, __fmul_rn(0.5f, ph));
    float x2 = __fadd_rn(pcx, __fmul_rn(0.5f, pw));
    float y2 = __fadd_rn(pcy, __fmul_rn(0.5f, ph));
    x1 = fminf(fmaxf(x1, 0.f), wmax);
    x2 = fminf(fmaxf(x2, 0.f), wmax);
    y1 = fminf(fmaxf(y1, 0.f), hmax);
    y2 = fminf(fmaxf(y2, 0.f), hmax);
    return make_float4(x1, y1, x2, y2);
}

// ---------------- fast path: fixed-threshold compact (float4, 2 anchors/thr) ---
__global__ void compact_fixed(const float* __restrict__ probs, u32* __restrict__ cntp,
                              u64* __restrict__ cand) {
    __shared__ u32 lcnt;
    __shared__ u32 lbase;
    int tid = threadIdx.x;
    int a0 = blockIdx.x * 512 + tid * 2;
    int b = blockIdx.y;
    if (tid == 0) lcnt = 0;
    __syncthreads();
    int lpos0 = -1, lpos1 = -1;
    u32 bits0 = 0, bits1 = 0;
    if (a0 < NA) {
        float4 v = *(const float4*)(probs + ((size_t)b * NA + a0) * 2);
        bits0 = __float_as_uint(v.y);
        bits1 = __float_as_uint(v.w);
        if (v.y >= THRF) lpos0 = (int)atomicAdd(&lcnt, 1u);
        if (v.w >= THRF) lpos1 = (int)atomicAdd(&lcnt, 1u);
    }
    __syncthreads();
    if (tid == 0) lbase = lcnt ? atomicAdd(&cntp[b * 64], lcnt) : 0u;
    __syncthreads();
    if (lpos0 >= 0) {
        u32 pos = lbase + (u32)lpos0;
        if (pos < CAP)
            cand[(size_t)b * CAP + pos] = ((u64)bits0 << 32) | (u32)(~(u32)a0);
    }
    if (lpos1 >= 0) {
        u32 pos = lbase + (u32)lpos1;
        if (pos < CAP)
            cand[(size_t)b * CAP + pos] = ((u64)bits1 << 32) | (u32)(~(u32)(a0 + 1));
    }
}

// ---------------- validate fast path; set per-batch fallback flags -------------
__global__ void check_kernel(u32* __restrict__ cntp, u32* __restrict__ flag) {
    int t = threadIdx.x;
    if (t < NB) {
        u32 c = cntp[t * 64];
        u32 bad = (c < (u32)PRE || c > (u32)CAP) ? 1u : 0u;
        flag[t * 64] = bad;
        if (bad) cntp[t * 64] = 0;
    }
}

// ---------------- gated fallback: zero hist (small grid, strided) --------------
__global__ void zero_hist(const u32* __restrict__ flag, u32* __restrict__ hist) {
    int b = blockIdx.y;
    if (flag[b * 64] == 0) return;
    int base = blockIdx.x * 4096;
    for (int k = 0; k < 16; ++k)
        hist[(size_t)b * 65536 + base + k * 256 + threadIdx.x] = 0;
}

// ---------------- gated fallback: histogram (small grid, strided) --------------
__global__ void hist_kernel(const u32* __restrict__ flag, const float* __restrict__ probs,
                            u32* __restrict__ hist) {
    int b = blockIdx.y;
    if (flag[b * 64] == 0) return;
    int base = blockIdx.x * 4096;
    for (int k = 0; k < 16; ++k) {
        int a = base + k * 256 + threadIdx.x;
        if (a < NA) {
            float2 pv = *(const float2*)(probs + ((size_t)b * NA + a) * 2);
            u32 bits = __float_as_uint(pv.y);
            atomicAdd(&hist[(size_t)b * 65536 + (bits >> 16)], 1u);
        }
    }
}

// ---------------- gated fallback: per-batch threshold --------------------------
__global__ __launch_bounds__(1024) void thresh_kernel(const u32* __restrict__ flag,
                                                      const u32* __restrict__ hist,
                                                      u32* __restrict__ thr) {
    int b = blockIdx.x;
    if (flag[b * 64] == 0) return;
    __shared__ u32 csum[1024];
    int t = threadIdx.x;
    const u32* h = hist + (size_t)b * 65536;
    u32 s = 0;
    for (int k = 0; k < 64; k++) s += h[t * 64 + k];
    csum[t] = s;
    __syncthreads();
    if (t == 0) {
        u32 cum = 0;
        int bucket = 0;
        for (int c = 1023; c >= 0; c--) {
            if (cum + csum[c] >= (u32)PRE) {
                u32 cum2 = cum;
                for (int k = 63; k >= 0; k--) {
                    cum2 += h[c * 64 + k];
                    if (cum2 >= (u32)PRE) { bucket = c * 64 + k; break; }
                }
                break;
            }
            cum += csum[c];
        }
        thr[b] = (u32)bucket << 16;
    }
}

// ---------------- gated fallback: staged compact (small grid, strided) ---------
__global__ void compact2_kernel(const u32* __restrict__ flag, const float* __restrict__ probs,
                                const u32* __restrict__ thr, u32* __restrict__ cntp,
                                u64* __restrict__ cand) {
    int b = blockIdx.y;
    if (flag[b * 64] == 0) return;
    __shared__ u32 lcnt;
    __shared__ u32 lbase;
    __shared__ u64 stage[4096];
    int tid = threadIdx.x;
    int base = blockIdx.x * 4096;
    if (tid == 0) lcnt = 0;
    __syncthreads();
    u32 tb = thr[b];
    for (int k = 0; k < 16; ++k) {
        int a = base + k * 256 + tid;
        if (a < NA) {
            float2 pv = *(const float2*)(probs + ((size_t)b * NA + a) * 2);
            u32 bits = __float_as_uint(pv.y);
            if (bits >= tb) {
                u32 p = atomicAdd(&lcnt, 1u);
                stage[p] = ((u64)bits << 32) | (u32)(~(u32)a);
            }
        }
    }
    __syncthreads();
    if (tid == 0) lbase = lcnt ? atomicAdd(&cntp[b * 64], lcnt) : 0u;
    __syncthreads();
    u32 n = lcnt;
    for (u32 i = tid; i < n; i += 256) {
        u32 pos = lbase + i;
        if (pos < CAP) cand[(size_t)b * CAP + pos] = stage[i];
    }
}

// ---------------- all-pairs rank, 4-way column-split (full occupancy) ----------
__global__ __launch_bounds__(256) void rank_kernel(const u64* __restrict__ cand,
                                                   const u32* __restrict__ cntp,
                                                   u32* __restrict__ rank4) {
    __shared__ u64 ckey[256];
    int rt = blockIdx.x;
    int cchunk = blockIdx.y;
    int b = blockIdx.z;
    int cnt = (int)min(cntp[b * 64], (u32)CAP);
    int t = threadIdx.x;
    const u64* cb = cand + (size_t)b * CAP;
    int row = rt * 256 + t;
    u64 rkey = (row < cnt) ? cb[row] : ~0ULL;
    u32 acc = 0;
    int c0 = cchunk * CCHUNK;
    int c1 = c0 + CCHUNK; if (c1 > cnt) c1 = cnt;
    for (int cc0 = c0; cc0 < c1; cc0 += 256) {
        __syncthreads();
        int ci = cc0 + t;
        ckey[t] = (ci < c1) ? cb[ci] : 0ULL;   // key 0 < any valid key -> contributes 0
        __syncthreads();
        int lim = c1 - cc0; if (lim > 256) lim = 256;
        int c = 0;
        for (; c + 4 <= lim; c += 4) {
            u64 k0 = ckey[c], k1 = ckey[c + 1], k2 = ckey[c + 2], k3 = ckey[c + 3];
            acc += (k0 > rkey) ? 1u : 0u;
            acc += (k1 > rkey) ? 1u : 0u;
            acc += (k2 > rkey) ? 1u : 0u;
            acc += (k3 > rkey) ? 1u : 0u;
        }
        for (; c < lim; ++c) acc += (ckey[c] > rkey) ? 1u : 0u;
    }
    rank4[(((size_t)b * 4 + cchunk) * CAP) + row] = acc;
}

// ---------------- scatter decode: gBoxes[rank[i]] = decode(cand[i]) ------------
__global__ void scatter_decode(const u64* __restrict__ cand, const u32* __restrict__ cntp,
                               const u32* __restrict__ rank4, const float* __restrict__ deltas,
                               const float* __restrict__ img_info, float4* __restrict__ gBoxes,
                               float* __restrict__ gAreas, float* __restrict__ out) {
    int i = blockIdx.x * 256 + threadIdx.x;     // 0..8191
    int b = blockIdx.y;
    if (i < POST) {
        float* o = out + ((size_t)b * POST + i) * 5;
        o[0] = (float)b; o[1] = 0.f; o[2] = 0.f; o[3] = 0.f; o[4] = 0.f;
    }
    int cnt = (int)min(cntp[b * 64], (u32)CAP);
    if (i >= cnt) return;
    u32 r = rank4[(((size_t)b * 4 + 0) * CAP) + i]
          + rank4[(((size_t)b * 4 + 1) * CAP) + i]
          + rank4[(((size_t)b * 4 + 2) * CAP) + i]
          + rank4[(((size_t)b * 4 + 3) * CAP) + i];
    if (r >= (u32)BOXSTRIDE) return;
    float hmax = __fsub_rn(img_info[b * 3 + 0], 1.0f);
    float wmax = __fsub_rn(img_info[b * 3 + 1], 1.0f);
    float4 bx = decode_box(cand[(size_t)b * CAP + i], b, deltas, hmax, wmax);
    gBoxes[(size_t)b * BOXSTRIDE + r] = bx;
    gAreas[(size_t)b * BOXSTRIDE + r] = box_area(bx);
}

// ---------------- full suppression bitmask (R19 structure + padded stores) -----
__global__ __launch_bounds__(256) void mask_kernel(const float4* __restrict__ gBoxes,
                                                   const float* __restrict__ gAreas,
                                                   u32* __restrict__ maskC) {
    __shared__ float4 cbox[256];
    __shared__ float  carea[256];
    __shared__ u32    tileOut[256][9];          // pad 8->9: conflict-free stores
    int lin = blockIdx.x;          // 0..299 over (rt, cc), cc >= rt
    int b = blockIdx.y;
    int rt = 0, rem = lin;
    while (rem >= NSEG - rt) { rem -= NSEG - rt; ++rt; }
    int cc = rt + rem;
    int t = threadIdx.x;
    int l = t & 63, q = t >> 6;
    const float4* gb = gBoxes + (size_t)b * BOXSTRIDE;
    const float*  ga = gAreas + (size_t)b * BOXSTRIDE;
    cbox[t] = gb[cc * 256 + t];
    carea[t] = ga[cc * 256 + t];
    float4 rb[4]; float ra[4]; int gr[4];
    #pragma unroll
    for (int j = 0; j < 4; ++j) {
        gr[j] = rt * 256 + l + 64 * j;
        rb[j] = gb[gr[j]];
        ra[j] = ga[gr[j]];
    }
    __syncthreads();
    int colbase = cc * 256 + q * 64;
    u32 a0[4] = {0u, 0u, 0u, 0u};
    u32 a1[4] = {0u, 0u, 0u, 0u};
    for (int c = 0; c < 32; ++c) {
        float4 cbx = cbox[q * 64 + c];        // wave-uniform -> broadcast
        float  cav = carea[q * 64 + c];
        int gc = colbase + c;
        #pragma unroll
        for (int j = 0; j < 4; ++j) {
            bool bit = (gc > gr[j]) && iou_supp(rb[j], ra[j], cbx, cav);
            a0[j] |= (bit ? 1u : 0u) << c;
        }
    }
    for (int c = 0; c < 32; ++c) {
        float4 cbx = cbox[q * 64 + 32 + c];
        float  cav = carea[q * 64 + 32 + c];
        int gc = colbase + 32 + c;
        #pragma unroll
        for (int j = 0; j < 4; ++j) {
            bool bit = (gc > gr[j]) && iou_supp(rb[j], ra[j], cbx, cav);
            a1[j] |= (bit ? 1u : 0u) << c;
        }
    }
    #pragma unroll
    for (int j = 0; j < 4; ++j) {
        tileOut[l + 64 * j][2 * q]     = a0[j];
        tileOut[l + 64 * j][2 * q + 1] = a1[j];
    }
    __syncthreads();
    uint4* rec = (uint4*)(maskC + (((size_t)b * NSEG + cc) * MROWS2 + rt * 256 + t) * 8);
    rec[0] = make_uint4(tileOut[t][0], tileOut[t][1], tileOut[t][2], tileOut[t][3]);
    rec[1] = make_uint4(tileOut[t][4], tileOut[t][5], tileOut[t][6], tileOut[t][7]);
}

// ---------------- pipelined mask-driven greedy NMS scan ------------------------
__global__ __launch_bounds__(1024) void nms_scan(const u32* __restrict__ maskC,
                                                 const float4* __restrict__ gBoxes,
                                                 float* __restrict__ out) {
    __shared__ u32 tile[2][SEG][8];
    __shared__ u32 aliveC[2][8];
    __shared__ u32 accW[2][8];
    __shared__ int keptList[POST];
    __shared__ int Kvar;

    int b = blockIdx.x;
    int t = threadIdx.x;
    int lane = t & 63;
    int w = t >> 6;
    const u32* mb = maskC + (size_t)b * NSEG * MROWS2 * 8;

    if (t < 8) {
        aliveC[0][t] = 0xFFFFFFFFu;
        accW[0][t] = 0u;
    } else if (t < 16) {
        accW[1][t - 8] = 0u;
    }
    if (t == 0) Kvar = 0;
    {   // prefetch tile 0
        const uint4* src = (const uint4*)mb;
        uint4* dst = (uint4*)&tile[0][0][0];
        for (int i = t; i < SEG * 2; i += 1024) dst[i] = src[i];
    }

    for (int s = 0; s < NSEG; ++s) {
        int bufc = s & 1, bufn = bufc ^ 1;
        __syncthreads();                    // barrier A
        int Kpre = Kvar;
        if (Kpre >= POST) break;            // uniform

        if (w == 0) {
            // ---- serial greedy scan of segment s (wave 0)
            u32 va = (lane < 8) ? aliveC[bufc][lane] : 0u;
            int KK = Kpre;
            while (true) {
                u64 balv = __ballot(va != 0u);
                if (balv == 0ULL) break;
                int wsel = __ffsll(balv) - 1;
                u32 word = __builtin_amdgcn_readlane(va, wsel);
                int r = (wsel << 5) + (__ffs(word) - 1);
                u32 trow = tile[bufc][r][lane & 7];
                if (lane == 8) keptList[KK] = s * SEG + r;
                u32 self = (lane == (r >> 5)) ? (1u << (r & 31)) : 0u;
                if (lane < 8) va &= ~(trow | self);
                ++KK;
                if (KK == POST) break;
            }
            if (lane == 0) Kvar = KK;
        } else if (s + 1 < NSEG) {
            // ---- bulk apply for chunk s+1: kepts [0, Kpre), 120 threads/word
            const u32* mbC = mb + (size_t)(s + 1) * (MROWS2 * 8);
            int wi = t & 7;
            int sub = (t - 64) >> 3;        // 0..119
            u32 part = 0;
            int j = sub;
            for (; j + 480 < Kpre; j += 480) {
                u32 x0 = mbC[(size_t)keptList[j] * 8 + wi];
                u32 x1 = mbC[(size_t)keptList[j + 120] * 8 + wi];
                u32 x2 = mbC[(size_t)keptList[j + 240] * 8 + wi];
                u32 x3 = mbC[(size_t)keptList[j + 360] * 8 + wi];
                part |= x0 | x1 | x2 | x3;
            }
            for (; j < Kpre; j += 120)
                part |= mbC[(size_t)keptList[j] * 8 + wi];
            if (part) atomicOr(&accW[bufn][wi], part);
            // ---- tile prefetch s+1 (8KB)
            const uint4* src = (const uint4*)(mbC + (size_t)(s + 1) * SEG * 8);
            uint4* dst = (uint4*)&tile[bufn][0][0];
            for (int i = t - 64; i < SEG * 2; i += 960) dst[i] = src[i];
        }
        __syncthreads();                    // barrier B

        int Kcur = Kvar;
        if (s + 1 < NSEG) {
            // ---- residual apply: delta kepts from scan(s)
            const u32* mbC = mb + (size_t)(s + 1) * (MROWS2 * 8);
            int delta8 = (Kcur - Kpre) * 8;
            for (int idx = t; idx < delta8; idx += 1024) {
                int j = Kpre + (idx >> 3);
                int wi = idx & 7;
                u32 x = mbC[(size_t)keptList[j] * 8 + wi];
                if (x) atomicOr(&accW[bufn][wi], x);
            }
        }
        __syncthreads();                    // barrier C

        if (s + 1 < NSEG) {
            if (t < 8) {
                int W = (s + 1) * 8 + t;
                u32 init = (W < 187) ? 0xFFFFFFFFu : ((W == 187) ? 0xFFFFu : 0u);
                aliveC[bufn][t] = init & ~accW[bufn][t];
            } else if (t < 16) {
                accW[bufc][t - 8] = 0u;     // recycle for chunk s+2
            }
        }
    }
    __syncthreads();

    int K = Kvar;
    const float4* gb = gBoxes + (size_t)b * BOXSTRIDE;
    for (int i = t; i < K; i += 1024) {
        int j = keptList[i];
        float4 bx = gb[j];
        float* o = out + ((size_t)b * POST + i) * 5;
        o[0] = (float)b; o[1] = bx.x; o[2] = bx.y; o[3] = bx.z; o[4] = bx.w;
    }
}

// ---------------- mid-ws tier: R14 pipelined fused lazy NMS --------------------
__global__ __launch_bounds__(1024) void nms_fused(const float4* __restrict__ gBoxes,
                                                  const float* __restrict__ gAreas,
                                                  float* __restrict__ out) {
    __shared__ float4 segBox[2][SEG];
    __shared__ float  segArea[2][SEG];
    __shared__ u32    tile[2][SEG][8];
    __shared__ u32    aliveW[2][8];
    __shared__ unsigned char aliveB[3][SEG];
    __shared__ float4 keptBox[KPAD];
    __shared__ float  keptArea[KPAD];
    __shared__ int    Kvar;

    int b = blockIdx.x;
    int t = threadIdx.x;
    int lane = t & 63;
    int w = t >> 6;
    if (t == 0) Kvar = 0;
    const float4* gb = gBoxes + (size_t)b * BOXSTRIDE;
    const float*  ga = gAreas + (size_t)b * BOXSTRIDE;

    if (t < SEG) {
        segBox[0][t] = gb[t];
        segArea[0][t] = ga[t];
    }
    __syncthreads();
    if (w < 10) {
        int u = NE_UNITS[w];
        int wc = u & 3, h = u >> 2;
        int c = wc * 64 + lane;
        float4 cb = segBox[0][c];
        float  ca = segArea[0][c];
        for (int r = h * 64; r < h * 64 + 64; ++r) {
            float4 rb = segBox[0][r];
            float  ra = segArea[0][r];
            bool bit = (r < c) && iou_supp(rb, ra, cb, ca);
            u64 bal = __ballot(bit);
            if (lane == 0) tile[0][r][2 * wc]     = (u32)bal;
            if (lane == 1) tile[0][r][2 * wc + 1] = (u32)(bal >> 32);
        }
    }
    if (t < SEG) {
        u64 bal = __ballot(true);
        if (lane == 0) aliveW[0][2 * w]     = (u32)bal;
        if (lane == 1) aliveW[0][2 * w + 1] = (u32)(bal >> 32);
    }

    int Kprev = 0;
    for (int s = 0; s < NSEG; ++s) {
        int bufc = s & 1, bufn = bufc ^ 1;
        __syncthreads();
        int Kcur = Kvar;
        if (Kcur >= POST) break;

        if (t < SEG) {
            if (s > 0) {
                bool al = aliveB[0][t] && aliveB[1][t] && aliveB[2][t];
                if (al && Kcur > Kprev) {
                    float4 rb = segBox[bufc][t];
                    float  ra = segArea[bufc][t];
                    int k = Kprev;
                    while (k < Kcur) {
                        bool d0 = iou_supp(keptBox[k], keptArea[k], rb, ra);
                        bool d1 = ((k + 1) < Kcur) & iou_supp(keptBox[k + 1], keptArea[k + 1], rb, ra);
                        bool d2 = ((k + 2) < Kcur) & iou_supp(keptBox[k + 2], keptArea[k + 2], rb, ra);
                        bool d3 = ((k + 3) < Kcur) & iou_supp(keptBox[k + 3], keptArea[k + 3], rb, ra);
                        if (d0 | d1 | d2 | d3) { al = false; break; }
                        k += 4;
                    }
                }
                u64 bal = __ballot(al);
                if (lane == 0) aliveW[bufc][2 * w]     = (u32)bal;
                if (lane == 1) aliveW[bufc][2 * w + 1] = (u32)(bal >> 32);
            }
            if (s + 1 < NSEG) {
                int g = (s + 1) * SEG + t;
                segBox[bufn][t] = gb[g];
                segArea[bufn][t] = ga[g];
                unsigned char v8 = (g < PRE) ? 1 : 0;
                aliveB[0][t] = v8; aliveB[1][t] = v8; aliveB[2][t] = v8;
            }
        }
        __syncthreads();

        if (w == 0) {
            int l = lane;
            u32 va = (l < 8) ? aliveW[bufc][l] : 0u;
            int KK = Kcur;
            while (true) {
                u64 balv = __ballot(va != 0u);
                if (balv == 0ULL) break;
                int wsel = __ffsll(balv) - 1;
                u32 word = __builtin_amdgcn_readlane(va, wsel);
                int r = (wsel << 5) + (__ffs(word) - 1);
                u32 trow = tile[bufc][r][l & 7];
                if (l >= 8 && l < 12)
                    ((float*)keptBox)[KK * 4 + (l - 8)] = ((const float*)segBox[bufc])[r * 4 + (l - 8)];
                if (l == 12) keptArea[KK] = segArea[bufc][r];
                u32 self = (l == (r >> 5)) ? (1u << (r & 31)) : 0u;
                if (l < 8) va &= ~(trow | self);
                ++KK;
                if (KK == POST) break;
            }
            if (l == 0) Kvar = KK;
        } else if (w <= 12) {
            if (s + 1 < NSEG && Kcur > 0) {
                int ww = w - 1;
                int rg = ww & 3;
                int kc = ww >> 2;
                int row = rg * 64 + lane;
                float4 rb = segBox[bufn][row];
                float  ra = segArea[bufn][row];
                bool dead = false, written = false;
                int q = 0;
                int k = kc;
                while (k < Kcur) {
                    int k1 = k + 3, k2 = k + 6, k3 = k + 9;
                    bool d0 = iou_supp(keptBox[k], keptArea[k], rb, ra);
                    bool d1 = (k1 < Kcur) & iou_supp(keptBox[k1], keptArea[k1], rb, ra);
                    bool d2 = (k2 < Kcur) & iou_supp(keptBox[k2], keptArea[k2], rb, ra);
                    bool d3 = (k3 < Kcur) & iou_supp(keptBox[k3], keptArea[k3], rb, ra);
                    dead |= (d0 | d1 | d2 | d3);
                    k += 12;
                    if (((++q) & 7) == 0) {
                        if (dead && !written) { aliveB[kc][row] = 0; written = true; }
                        u32 comb = (u32)aliveB[0][row] & (u32)aliveB[1][row] & (u32)aliveB[2][row];
                        if (__ballot(comb != 0u) == 0ULL) break;
                    }
                }
                if (dead && !written) aliveB[kc][row] = 0;
            }
        } else {
            if (s + 1 < NSEG) {
                int g3 = w - 13;
                int nu = TILE_N[g3];
                for (int ui = 0; ui < nu; ++ui) {
                    int u = TILE_U[g3][ui];
                    int wc = u & 3, h = u >> 2;
                    int c = wc * 64 + lane;
                    float4 cb = segBox[bufn][c];
                    float  ca = segArea[bufn][c];
                    for (int r = h * 64; r < h * 64 + 64; ++r) {
                        float4 rb = segBox[bufn][r];
                        float  ra = segArea[bufn][r];
                        bool bit = (r < c) && iou_supp(rb, ra, cb, ca);
                        u64 bal = __ballot(bit);
                        if (lane == 0) tile[bufn][r][2 * wc]     = (u32)bal;
                        if (lane == 1) tile[bufn][r][2 * wc + 1] = (u32)(bal >> 32);
                    }
                }
            }
        }
        Kprev = Kcur;
    }
    __syncthreads();

    int K = Kvar;
    for (int s2 = t; s2 < POST; s2 += 1024) {
        float* o = out + ((size_t)b * POST + s2) * 5;
        if (s2 < K) {
            float4 bx = keptBox[s2];
            o[0] = (float)b; o[1] = bx.x; o[2] = bx.y; o[3] = bx.z; o[4] = bx.w;
        } else {
            o[0] = (float)b; o[1] = 0.f; o[2] = 0.f; o[3] = 0.f; o[4] = 0.f;
        }
    }
}

// ---------------- fallback: monolithic sort+decode+NMS (small ws) --------------
__global__ __launch_bounds__(1024) void final_kernel(const u64* __restrict__ cand, const u32* __restrict__ cntp,
                             const float* __restrict__ deltas, const float* __restrict__ img_info,
                             float* __restrict__ out) {
    __shared__ union {
        u64 keys[CAP];
        struct {
            float boxes[PRE][4];
            float areas[PRE];
            u32   alive[192];
        } n;
    } sh;
    __shared__ int s_next;

    int b = blockIdx.x;
    int tid = threadIdx.x;

    for (int s = tid; s < POST; s += 1024) {
        float* o = out + ((size_t)b * POST + s) * 5;
        o[0] = (float)b; o[1] = 0.f; o[2] = 0.f; o[3] = 0.f; o[4] = 0.f;
    }

    int n = (int)min(cntp[b * 64], (u32)CAP);
    for (int i = tid; i < CAP; i += 1024)
        sh.keys[i] = (i < n) ? cand[(size_t)b * CAP + i] : 0ULL;
    __syncthreads();

    for (int k = 2; k <= CAP; k <<= 1) {
        for (int j = k >> 1; j > 0; j >>= 1) {
            for (int i = tid; i < CAP; i += 1024) {
                int ixj = i ^ j;
                if (ixj > i) {
                    u64 x = sh.keys[i], y = sh.keys[ixj];
                    bool desc = ((i & k) == 0);
                    if (desc ? (x < y) : (x > y)) { sh.keys[i] = y; sh.keys[ixj] = x; }
                }
            }
            __syncthreads();
        }
    }

    u32 myIdx[6];
    #pragma unroll
    for (int r = 0; r < 6; r++) {
        int i = tid + r * 1024;
        if (i < PRE) myIdx[r] = ~(u32)(sh.keys[i]);
    }
    __syncthreads();

    float hmax = __fsub_rn(img_info[b * 3 + 0], 1.0f);
    float wmax = __fsub_rn(img_info[b * 3 + 1], 1.0f);

    #pragma unroll
    for (int r = 0; r < 6; r++) {
        int i = tid + r * 1024;
        if (i < PRE) {
            int a = (int)myIdx[r];
            float a0, a1, a2, a3;
            anchor_at(a, a0, a1, a2, a3);
            const float4 d4 = *(const float4*)(deltas + ((size_t)b * NA + a) * 4);
            float w  = __fadd_rn(__fsub_rn(a2, a0), 1.0f);
            float h  = __fadd_rn(__fsub_rn(a3, a1), 1.0f);
            float cx = __fadd_rn(a0, __fmul_rn(0.5f, w));
            float cy = __fadd_rn(a1, __fmul_rn(0.5f, h));
            float pcx = __fadd_rn(__fmul_rn(d4.x, w), cx);
            float pcy = __fadd_rn(__fmul_rn(d4.y, h), cy);
            float pw  = __fmul_rn((float)exp((double)d4.z), w);
            float ph  = __fmul_rn((float)exp((double)d4.w), h);
            float x1 = __fsub_rn(pcx, __fmul_rn(0.5f, pw));
            float y1 = __fsub_rn(pcy, __fmul_rn(0.5f, ph));
            float x2 = __fadd_rn(pcx, __fmul_rn(0.5f, pw));
            float y2 = __fadd_rn(pcy, __fmul_rn(0.5f, ph));
            x1 = fminf(fmaxf(x1, 0.f), wmax);
            x2 = fminf(fmaxf(x2, 0.f), wmax);
            y1 = fminf(fmaxf(y1, 0.f), hmax);
            y2 = fminf(fmaxf(y2, 0.f), hmax);
            sh.n.boxes[i][0] = x1; sh.n.boxes[i][1] = y1;
            sh.n.boxes[i][2] = x2; sh.n.boxes[i][3] = y2;
            sh.n.areas[i] = __fmul_rn(__fadd_rn(__fsub_rn(x2, x1), 1.0f),
                                      __fadd_rn(__fsub_rn(y2, y1), 1.0f));
        }
    }

    for (int wdi = tid; wdi < 192; wdi += 1024) {
        u32 v = 0xFFFFFFFFu;
        if (wdi == 187) v = 0x0000FFFFu;
        if (wdi > 187)  v = 0u;
        sh.n.alive[wdi] = v;
    }
    __syncthreads();

    int kept = 0;
    int scanWord = 0;
    while (kept < POST) {
        if (tid == 0) {
            int found = -1;
            while (scanWord < 188) {
                u32 wv = sh.n.alive[scanWord];
                if (wv) { found = scanWord * 32 + (__ffs(wv) - 1); break; }
                scanWord++;
            }
            s_next = found;
        }
        __syncthreads();
        int i = s_next;
        if (i < 0) break;
        float bx1 = sh.n.boxes[i][0], by1 = sh.n.boxes[i][1];
        float bx2 = sh.n.boxes[i][2], by2 = sh.n.boxes[i][3];
        float bar = sh.n.areas[i];
        if (tid == 0) {
            float* o = out + ((size_t)b * POST + kept) * 5;
            o[1] = bx1; o[2] = by1; o[3] = bx2; o[4] = by2;
            atomicAnd(&sh.n.alive[i >> 5], ~(1u << (i & 31)));
        }
        for (int j = i + 1 + tid; j < PRE; j += 1024) {
            float x1 = sh.n.boxes[j][0], y1 = sh.n.boxes[j][1];
            float x2 = sh.n.boxes[j][2], y2 = sh.n.boxes[j][3];
            float xx1 = fmaxf(x1, bx1), yy1 = fmaxf(y1, by1);
            float xx2 = fminf(x2, bx2), yy2 = fminf(y2, by2);
            float iw = fmaxf(__fadd_rn(__fsub_rn(xx2, xx1), 1.0f), 0.f);
            float ih = fmaxf(__fadd_rn(__fsub_rn(yy2, yy1), 1.0f), 0.f);
            float inter = __fmul_rn(iw, ih);
            float denom = __fsub_rn(__fadd_rn(sh.n.areas[j], bar), inter);
            float iou = __fdiv_rn(inter, denom);
            if (iou > 0.7f) atomicAnd(&sh.n.alive[j >> 5], ~(1u << (j & 31)));
        }
        kept++;
        __syncthreads();
    }
}

// ---------------- launcher -----------------------------------------------------
extern "C" void kernel_launch(void* const* d_in, const int* in_sizes, int n_in,
                              void* d_out, int out_size, void* d_ws, size_t ws_size,
                              hipStream_t stream) {
    const float* probs    = (const float*)d_in[0];
    const float* deltas   = (const float*)d_in[1];
    const float* img_info = (const float*)d_in[2];
    float* out = (float*)d_out;

    char* ws = (char*)d_ws;
    size_t off = 0;
    u32* cntp = (u32*)(ws + off); off += (size_t)NB * 64 * sizeof(u32);
    u32* flag = (u32*)(ws + off); off += (size_t)NB * 64 * sizeof(u32);
    u32* thr  = (u32*)(ws + off); off += 4096;
    u32* hist = (u32*)(ws + off); off += (size_t)NB * 65536 * sizeof(u32);
    u64* cand = (u64*)(ws + off); off += (size_t)NB * CAP * sizeof(u64);
    u32* rank4 = (u32*)(ws + off); off += (size_t)NB * 4 * CAP * sizeof(u32);  // 2 MiB
    float4* gBoxes = (float4*)(ws + off); off += (size_t)NB * BOXSTRIDE * sizeof(float4);
    float*  gAreas = (float*)(ws + off);  off += (size_t)NB * BOXSTRIDE * sizeof(float);
    size_t tier1 = off;
    u32* maskC = (u32*)(ws + off); off += (size_t)NB * NSEG * MROWS2 * 8 * sizeof(u32); // 75.5 MiB
    size_t tier2 = off;

    if (ws_size >= tier1) {
        hipMemsetAsync(cntp, 0, (size_t)NB * 64 * sizeof(u32), stream);
        compact_fixed<<<dim3((NA + 511) / 512, NB), 256, 0, stream>>>(probs, cntp, cand);
        check_kernel<<<1, 64, 0, stream>>>(cntp, flag);
        zero_hist<<<dim3(16, NB), 256, 0, stream>>>(flag, hist);
        hist_kernel<<<dim3(64, NB), 256, 0, stream>>>(flag, probs, hist);
        thresh_kernel<<<NB, 1024, 0, stream>>>(flag, hist, thr);
        compact2_kernel<<<dim3(64, NB), 256, 0, stream>>>(flag, probs, thr, cntp, cand);
        rank_kernel<<<dim3(CAP / 256, 4, NB), 256, 0, stream>>>(cand, cntp, rank4);
        scatter_decode<<<dim3(CAP / 256, NB), 256, 0, stream>>>(cand, cntp, rank4, deltas,
                                                                img_info, gBoxes, gAreas, out);
        if (ws_size >= tier2) {
            mask_kernel<<<dim3(300, NB), 256, 0, stream>>>(gBoxes, gAreas, maskC);
            nms_scan<<<NB, 1024, 0, stream>>>(maskC, gBoxes, out);
        } else {
            nms_fused<<<NB, 1024, 0, stream>>>(gBoxes, gAreas, out);
        }
    } else {
        hipMemsetAsync(cntp, 0, (size_t)NB * 64 * sizeof(u32), stream);
        hipMemsetAsync(flag, 1, (size_t)NB * 64 * sizeof(u32), stream);
        hipMemsetAsync(hist, 0, (size_t)NB * 65536 * sizeof(u32), stream);
        hist_kernel<<<dim3(64, NB), 256, 0, stream>>>(flag, probs, hist);
        thresh_kernel<<<NB, 1024, 0, stream>>>(flag, hist, thr);
        compact2_kernel<<<dim3(64, NB), 256, 0, stream>>>(flag, probs, thr, cntp, cand);
        final_kernel<<<NB, 1024, 0, stream>>>(cand, cntp, deltas, img_info, out);
    }
}